// Round 1
// baseline (1500.716 us; speedup 1.0000x reference)
//
#include <hip/hip_runtime.h>
#include <math.h>

#define N_NODES  100000
#define N_EDGES  3200000
#define N_GRAPHS 256

// DIMS = [38, 64, 32, 16]

__device__ __forceinline__ float fast_tanh(float x) {
    x = fminf(20.f, fmaxf(-20.f, x));
    float e = __expf(2.f * x);
    return (e - 1.f) / (e + 1.f);
}

// -------- scatter: out[dst[e]][d] += feat[src[e]][d] --------
template<int DIM>
__global__ __launch_bounds__(256) void k_scatter(const float* __restrict__ feat,
                                                 const int* __restrict__ src,
                                                 const int* __restrict__ dst,
                                                 float* __restrict__ out) {
    int idx = blockIdx.x * 256 + threadIdx.x;           // (e, d)
    if (idx >= N_EDGES * DIM) return;
    int e = idx / DIM;
    int d = idx - e * DIM;
    int s = src[e];
    int t = dst[e];
    unsafeAtomicAdd(&out[t * DIM + d], feat[s * DIM + d]);
}

// -------- layer0 update: h1 = tanh(agg@Wrel^T + b + x@Wroot^T), 38 -> 64 --------
__global__ __launch_bounds__(256) void k_update0(const float* __restrict__ agg,
                                                 const float* __restrict__ x,
                                                 const float* __restrict__ Wrel,
                                                 const float* __restrict__ b,
                                                 const float* __restrict__ Wroot,
                                                 float* __restrict__ h1) {
    __shared__ float sWrel[64 * 38];
    __shared__ float sWroot[64 * 38];
    __shared__ float sb[64];
    for (int i = threadIdx.x; i < 64 * 38; i += 256) { sWrel[i] = Wrel[i]; sWroot[i] = Wroot[i]; }
    if (threadIdx.x < 64) sb[threadIdx.x] = b[threadIdx.x];
    __syncthreads();

    int idx = blockIdx.x * 256 + threadIdx.x;           // (n, o) o in [0,64)
    int n = idx >> 6;
    int o = idx & 63;
    if (n >= N_NODES) return;
    const float* ar = agg + n * 38;
    const float* xr = x   + n * 38;
    float acc = sb[o];
#pragma unroll
    for (int d = 0; d < 38; ++d)
        acc += ar[d] * sWrel[o * 38 + d] + xr[d] * sWroot[o * 38 + d];
    h1[idx] = fast_tanh(acc);
}

// -------- plain linear: out = in @ W^T  (no bias) --------
template<int DIN, int DOUT>
__global__ __launch_bounds__(256) void k_linear(const float* __restrict__ in,
                                                const float* __restrict__ W,
                                                float* __restrict__ out) {
    __shared__ float sW[DOUT * DIN];
    for (int i = threadIdx.x; i < DOUT * DIN; i += 256) sW[i] = W[i];
    __syncthreads();
    int idx = blockIdx.x * 256 + threadIdx.x;           // (n, o)
    int n = idx / DOUT;
    int o = idx - n * DOUT;
    if (n >= N_NODES) return;
    const float* r = in + n * DIN;
    float acc = 0.f;
#pragma unroll
    for (int k = 0; k < DIN; ++k) acc += r[k] * sW[o * DIN + k];
    out[idx] = acc;
}

// -------- mid update: h = tanh(agg + b + hin@Wroot^T) --------
template<int DIN, int DOUT>
__global__ __launch_bounds__(256) void k_update_mid(const float* __restrict__ agg,
                                                    const float* __restrict__ hin,
                                                    const float* __restrict__ Wroot,
                                                    const float* __restrict__ b,
                                                    float* __restrict__ out) {
    __shared__ float sW[DOUT * DIN];
    __shared__ float sb[DOUT];
    for (int i = threadIdx.x; i < DOUT * DIN; i += 256) sW[i] = Wroot[i];
    if (threadIdx.x < DOUT) sb[threadIdx.x] = b[threadIdx.x];
    __syncthreads();
    int idx = blockIdx.x * 256 + threadIdx.x;           // (n, o)
    int n = idx / DOUT;
    int o = idx - n * DOUT;
    if (n >= N_NODES) return;
    const float* r = hin + n * DIN;
    float acc = agg[idx] + sb[o];
#pragma unroll
    for (int k = 0; k < DIN; ++k) acc += r[k] * sW[o * DIN + k];
    out[idx] = fast_tanh(acc);
}

// -------- final update + fused mean-pool accumulation --------
// h3 = agg + b + h2@Wroot^T (32->16), then psum[batch[n]] += h3, pcnt[batch[n]] += 1
__global__ __launch_bounds__(256) void k_update2_pool(const float* __restrict__ agg,
                                                      const float* __restrict__ h2,
                                                      const float* __restrict__ Wroot,
                                                      const float* __restrict__ b,
                                                      const int* __restrict__ batch,
                                                      float* __restrict__ psum,
                                                      float* __restrict__ pcnt) {
    __shared__ float sW[16 * 32];
    __shared__ float sb[16];
    __shared__ float slot[16][16];   // 16 graph slots x 16 dims
    __shared__ float scnt[16];
    __shared__ int sgmin;
    int tid = threadIdx.x;
    for (int i = tid; i < 16 * 32; i += 256) sW[i] = Wroot[i];
    if (tid < 16) { sb[tid] = b[tid]; scnt[tid] = 0.f; }
    ((float*)slot)[tid] = 0.f;       // exactly 256 entries
    int n0 = blockIdx.x * 16;
    if (tid == 0) sgmin = batch[n0];
    __syncthreads();

    int n = n0 + (tid >> 4);
    int o = tid & 15;
    if (n < N_NODES) {
        int g = batch[n];
        const float* r = h2 + n * 32;
        float acc = agg[n * 16 + o] + sb[o];
#pragma unroll
        for (int k = 0; k < 32; ++k) acc += r[k] * sW[o * 32 + k];
        int rel = g - sgmin;
        if (rel < 16) {
            atomicAdd(&slot[rel][o], acc);
            if (o == 0) atomicAdd(&scnt[rel], 1.f);
        } else {
            unsafeAtomicAdd(&psum[g * 16 + o], acc);
            if (o == 0) unsafeAtomicAdd(&pcnt[g], 1.f);
        }
    }
    __syncthreads();

    // flush slots
    int s = tid >> 4;                 // 0..15
    int g = sgmin + s;
    if (g < N_GRAPHS) {
        unsafeAtomicAdd(&psum[g * 16 + o], slot[s][o]);
        if (o == 0) unsafeAtomicAdd(&pcnt[g], scnt[s]);
    }
}

__global__ __launch_bounds__(256) void k_finalize(const float* __restrict__ psum,
                                                  const float* __restrict__ pcnt,
                                                  float* __restrict__ out) {
    int idx = blockIdx.x * 256 + threadIdx.x;
    if (idx >= N_GRAPHS * 16) return;
    int g = idx >> 4;
    out[idx] = fast_tanh(psum[idx] / fmaxf(pcnt[g], 1.f));
}

extern "C" void kernel_launch(void* const* d_in, const int* in_sizes, int n_in,
                              void* d_out, int out_size, void* d_ws, size_t ws_size,
                              hipStream_t stream) {
    const float* x      = (const float*)d_in[0];
    const int*   eidx   = (const int*)d_in[1];
    const int*   src    = eidx;
    const int*   dst    = eidx + N_EDGES;
    const int*   batch  = (const int*)d_in[2];
    const float* Wrel0  = (const float*)d_in[3];
    const float* b0     = (const float*)d_in[4];
    const float* Wroot0 = (const float*)d_in[5];
    const float* Wrel1  = (const float*)d_in[6];
    const float* b1     = (const float*)d_in[7];
    const float* Wroot1 = (const float*)d_in[8];
    const float* Wrel2  = (const float*)d_in[9];
    const float* b2     = (const float*)d_in[10];
    const float* Wroot2 = (const float*)d_in[11];
    float* out = (float*)d_out;

    float* ws   = (float*)d_ws;
    float* agg  = ws;                                  // N*38 floats (reused: 38/32/16)
    float* h1   = agg + (size_t)N_NODES * 38;          // N*64
    float* y    = h1  + (size_t)N_NODES * 64;          // N*32 (y1; later y2 uses N*16)
    float* h2   = y   + (size_t)N_NODES * 32;          // N*32
    float* psum = h2  + (size_t)N_NODES * 32;          // 256*16
    float* pcnt = psum + (size_t)N_GRAPHS * 16;        // 256

    // ---- Layer 0: aggregate raw x (38-dim), then fused double-linear ----
    hipMemsetAsync(agg, 0, sizeof(float) * (size_t)N_NODES * 38, stream);
    k_scatter<38><<<(N_EDGES * 38 + 255) / 256, 256, 0, stream>>>(x, src, dst, agg);
    k_update0<<<(N_NODES * 64 + 255) / 256, 256, 0, stream>>>(agg, x, Wrel0, b0, Wroot0, h1);

    // ---- Layer 1: transform first (64->32), aggregate 32-dim ----
    k_linear<64, 32><<<(N_NODES * 32 + 255) / 256, 256, 0, stream>>>(h1, Wrel1, y);
    hipMemsetAsync(agg, 0, sizeof(float) * (size_t)N_NODES * 32, stream);
    k_scatter<32><<<(N_EDGES * 32 + 255) / 256, 256, 0, stream>>>(y, src, dst, agg);
    k_update_mid<64, 32><<<(N_NODES * 32 + 255) / 256, 256, 0, stream>>>(agg, h1, Wroot1, b1, h2);

    // ---- Layer 2: transform first (32->16), aggregate 16-dim, fused pool ----
    k_linear<32, 16><<<(N_NODES * 16 + 255) / 256, 256, 0, stream>>>(h2, Wrel2, y);
    hipMemsetAsync(agg, 0, sizeof(float) * (size_t)N_NODES * 16, stream);
    k_scatter<16><<<(N_EDGES * 16 + 255) / 256, 256, 0, stream>>>(y, src, dst, agg);
    hipMemsetAsync(psum, 0, sizeof(float) * (N_GRAPHS * 16 + N_GRAPHS), stream);
    k_update2_pool<<<(N_NODES + 15) / 16, 256, 0, stream>>>(agg, h2, Wroot2, b2, batch, psum, pcnt);

    k_finalize<<<(N_GRAPHS * 16 + 255) / 256, 256, 0, stream>>>(psum, pcnt, out);
}

// Round 2
// 1070.773 us; speedup vs baseline: 1.4015x; 1.4015x over previous
//
#include <hip/hip_runtime.h>
#include <math.h>

#define N_NODES  100000
#define N_EDGES  3200000
#define N_GRAPHS 256

// DIMS = [38, 64, 32, 16]

#define SCAN_ELEMS 1024
#define N_SCAN_BLOCKS ((N_NODES + SCAN_ELEMS - 1) / SCAN_ELEMS)   // 98

__device__ __forceinline__ float fast_tanh(float x) {
    x = fminf(20.f, fmaxf(-20.f, x));
    float e = __expf(2.f * x);
    return (e - 1.f) / (e + 1.f);
}

// ---------------- CSR build ----------------
__global__ __launch_bounds__(256) void k_count(const int* __restrict__ dst,
                                               int* __restrict__ deg) {
    int e = blockIdx.x * 256 + threadIdx.x;
    if (e >= N_EDGES) return;
    atomicAdd(&deg[dst[e]], 1);
}

// block-local exclusive scan over 1024 elements (4 per thread); block sums out
__global__ __launch_bounds__(256) void k_scan_local(const int* __restrict__ deg,
                                                    int* __restrict__ excl,
                                                    int* __restrict__ bsum) {
    __shared__ int sd[256];
    int tid = threadIdx.x;
    int base = blockIdx.x * SCAN_ELEMS + tid * 4;
    int v0 = (base + 0 < N_NODES) ? deg[base + 0] : 0;
    int v1 = (base + 1 < N_NODES) ? deg[base + 1] : 0;
    int v2 = (base + 2 < N_NODES) ? deg[base + 2] : 0;
    int v3 = (base + 3 < N_NODES) ? deg[base + 3] : 0;
    int s = v0 + v1 + v2 + v3;
    int val = s;
    sd[tid] = val;
    __syncthreads();
#pragma unroll
    for (int off = 1; off < 256; off <<= 1) {
        int t = (tid >= off) ? sd[tid - off] : 0;
        __syncthreads();
        val += t;
        sd[tid] = val;
        __syncthreads();
    }
    int ex = val - s;
    if (base + 0 < N_NODES) excl[base + 0] = ex;
    if (base + 1 < N_NODES) excl[base + 1] = ex + v0;
    if (base + 2 < N_NODES) excl[base + 2] = ex + v0 + v1;
    if (base + 3 < N_NODES) excl[base + 3] = ex + v0 + v1 + v2;
    if (tid == 255) bsum[blockIdx.x] = val;
}

// single block: exclusive scan of the 98 block sums (in place)
__global__ __launch_bounds__(128) void k_scan_bsum(int* __restrict__ bsum) {
    __shared__ int sd[128];
    int tid = threadIdx.x;
    int v = (tid < N_SCAN_BLOCKS) ? bsum[tid] : 0;
    int val = v;
    sd[tid] = val;
    __syncthreads();
#pragma unroll
    for (int off = 1; off < 128; off <<= 1) {
        int t = (tid >= off) ? sd[tid - off] : 0;
        __syncthreads();
        val += t;
        sd[tid] = val;
        __syncthreads();
    }
    if (tid < N_SCAN_BLOCKS) bsum[tid] = val - v;
}

// rowptr[i] = excl[i] + bsum[block]; pos[i] = same (fill cursor)
__global__ __launch_bounds__(256) void k_scan_apply(int* __restrict__ rowptr,
                                                    const int* __restrict__ bsum,
                                                    int* __restrict__ pos) {
    int i = blockIdx.x * 256 + threadIdx.x;
    if (i >= N_NODES) return;
    int v = rowptr[i] + bsum[i >> 10];
    rowptr[i] = v;
    pos[i] = v;
}

__global__ __launch_bounds__(256) void k_fill(const int* __restrict__ src,
                                              const int* __restrict__ dst,
                                              int* __restrict__ pos,
                                              int* __restrict__ elist) {
    int e = blockIdx.x * 256 + threadIdx.x;
    if (e >= N_EDGES) return;
    int slot = atomicAdd(&pos[dst[e]], 1);
    elist[slot] = src[e];
}

// ---------------- gather aggregation: agg[n][d] = sum_{j in in(n)} feat[elist[j]][d] ----------------
// after k_fill, pos[n] == row end
template<int DIM>
__global__ __launch_bounds__(256) void k_gather(const float* __restrict__ feat,
                                                const int* __restrict__ rowptr,
                                                const int* __restrict__ rowend,
                                                const int* __restrict__ elist,
                                                float* __restrict__ agg) {
    int idx = blockIdx.x * 256 + threadIdx.x;
    if (idx >= N_NODES * DIM) return;
    int n = idx / DIM;
    int d = idx - n * DIM;
    int j = rowptr[n];
    int e = rowend[n];
    float acc = 0.f;
    for (; j + 1 < e; j += 2) {
        int s0 = elist[j];
        int s1 = elist[j + 1];
        acc += feat[s0 * DIM + d];
        acc += feat[s1 * DIM + d];
    }
    if (j < e) acc += feat[elist[j] * DIM + d];
    agg[idx] = acc;
}

// -------- layer0 update: h1 = tanh(agg@Wrel^T + b + x@Wroot^T), 38 -> 64 --------
__global__ __launch_bounds__(256) void k_update0(const float* __restrict__ agg,
                                                 const float* __restrict__ x,
                                                 const float* __restrict__ Wrel,
                                                 const float* __restrict__ b,
                                                 const float* __restrict__ Wroot,
                                                 float* __restrict__ h1) {
    __shared__ float sWrel[64 * 38];
    __shared__ float sWroot[64 * 38];
    __shared__ float sb[64];
    for (int i = threadIdx.x; i < 64 * 38; i += 256) { sWrel[i] = Wrel[i]; sWroot[i] = Wroot[i]; }
    if (threadIdx.x < 64) sb[threadIdx.x] = b[threadIdx.x];
    __syncthreads();

    int idx = blockIdx.x * 256 + threadIdx.x;           // (n, o) o in [0,64)
    int n = idx >> 6;
    int o = idx & 63;
    if (n >= N_NODES) return;
    const float* ar = agg + n * 38;
    const float* xr = x   + n * 38;
    float acc = sb[o];
#pragma unroll
    for (int d = 0; d < 38; ++d)
        acc += ar[d] * sWrel[o * 38 + d] + xr[d] * sWroot[o * 38 + d];
    h1[idx] = fast_tanh(acc);
}

// -------- plain linear: out = in @ W^T  (no bias) --------
template<int DIN, int DOUT>
__global__ __launch_bounds__(256) void k_linear(const float* __restrict__ in,
                                                const float* __restrict__ W,
                                                float* __restrict__ out) {
    __shared__ float sW[DOUT * DIN];
    for (int i = threadIdx.x; i < DOUT * DIN; i += 256) sW[i] = W[i];
    __syncthreads();
    int idx = blockIdx.x * 256 + threadIdx.x;           // (n, o)
    int n = idx / DOUT;
    int o = idx - n * DOUT;
    if (n >= N_NODES) return;
    const float* r = in + n * DIN;
    float acc = 0.f;
#pragma unroll
    for (int k = 0; k < DIN; ++k) acc += r[k] * sW[o * DIN + k];
    out[idx] = acc;
}

// -------- mid update: h = tanh(agg + b + hin@Wroot^T) --------
template<int DIN, int DOUT>
__global__ __launch_bounds__(256) void k_update_mid(const float* __restrict__ agg,
                                                    const float* __restrict__ hin,
                                                    const float* __restrict__ Wroot,
                                                    const float* __restrict__ b,
                                                    float* __restrict__ out) {
    __shared__ float sW[DOUT * DIN];
    __shared__ float sb[DOUT];
    for (int i = threadIdx.x; i < DOUT * DIN; i += 256) sW[i] = Wroot[i];
    if (threadIdx.x < DOUT) sb[threadIdx.x] = b[threadIdx.x];
    __syncthreads();
    int idx = blockIdx.x * 256 + threadIdx.x;           // (n, o)
    int n = idx / DOUT;
    int o = idx - n * DOUT;
    if (n >= N_NODES) return;
    const float* r = hin + n * DIN;
    float acc = agg[idx] + sb[o];
#pragma unroll
    for (int k = 0; k < DIN; ++k) acc += r[k] * sW[o * DIN + k];
    out[idx] = fast_tanh(acc);
}

// -------- final update + fused mean-pool accumulation --------
__global__ __launch_bounds__(256) void k_update2_pool(const float* __restrict__ agg,
                                                      const float* __restrict__ h2,
                                                      const float* __restrict__ Wroot,
                                                      const float* __restrict__ b,
                                                      const int* __restrict__ batch,
                                                      float* __restrict__ psum,
                                                      float* __restrict__ pcnt) {
    __shared__ float sW[16 * 32];
    __shared__ float sb[16];
    __shared__ float slot[16][16];   // 16 graph slots x 16 dims
    __shared__ float scnt[16];
    __shared__ int sgmin;
    int tid = threadIdx.x;
    for (int i = tid; i < 16 * 32; i += 256) sW[i] = Wroot[i];
    if (tid < 16) { sb[tid] = b[tid]; scnt[tid] = 0.f; }
    ((float*)slot)[tid] = 0.f;       // exactly 256 entries
    int n0 = blockIdx.x * 16;
    if (tid == 0) sgmin = batch[n0];
    __syncthreads();

    int n = n0 + (tid >> 4);
    int o = tid & 15;
    if (n < N_NODES) {
        int g = batch[n];
        const float* r = h2 + n * 32;
        float acc = agg[n * 16 + o] + sb[o];
#pragma unroll
        for (int k = 0; k < 32; ++k) acc += r[k] * sW[o * 32 + k];
        int rel = g - sgmin;
        if (rel < 16) {
            atomicAdd(&slot[rel][o], acc);
            if (o == 0) atomicAdd(&scnt[rel], 1.f);
        } else {
            unsafeAtomicAdd(&psum[g * 16 + o], acc);
            if (o == 0) unsafeAtomicAdd(&pcnt[g], 1.f);
        }
    }
    __syncthreads();

    int s = tid >> 4;                 // 0..15
    int g = sgmin + s;
    if (g < N_GRAPHS) {
        unsafeAtomicAdd(&psum[g * 16 + o], slot[s][o]);
        if (o == 0) unsafeAtomicAdd(&pcnt[g], scnt[s]);
    }
}

__global__ __launch_bounds__(256) void k_finalize(const float* __restrict__ psum,
                                                  const float* __restrict__ pcnt,
                                                  float* __restrict__ out) {
    int idx = blockIdx.x * 256 + threadIdx.x;
    if (idx >= N_GRAPHS * 16) return;
    int g = idx >> 4;
    out[idx] = fast_tanh(psum[idx] / fmaxf(pcnt[g], 1.f));
}

extern "C" void kernel_launch(void* const* d_in, const int* in_sizes, int n_in,
                              void* d_out, int out_size, void* d_ws, size_t ws_size,
                              hipStream_t stream) {
    const float* x      = (const float*)d_in[0];
    const int*   eidx   = (const int*)d_in[1];
    const int*   src    = eidx;
    const int*   dst    = eidx + N_EDGES;
    const int*   batch  = (const int*)d_in[2];
    const float* Wrel0  = (const float*)d_in[3];
    const float* b0     = (const float*)d_in[4];
    const float* Wroot0 = (const float*)d_in[5];
    const float* Wrel1  = (const float*)d_in[6];
    const float* b1     = (const float*)d_in[7];
    const float* Wroot1 = (const float*)d_in[8];
    const float* Wrel2  = (const float*)d_in[9];
    const float* b2     = (const float*)d_in[10];
    const float* Wroot2 = (const float*)d_in[11];
    float* out = (float*)d_out;

    // ---- workspace layout ----
    float* ws   = (float*)d_ws;
    float* agg  = ws;                                  // N*38 floats (reused: 38/32/16)
    float* h1   = agg + (size_t)N_NODES * 38;          // N*64
    float* y    = h1  + (size_t)N_NODES * 64;          // N*32 max
    float* h2   = y   + (size_t)N_NODES * 32;          // N*32
    float* psum = h2  + (size_t)N_NODES * 32;          // 256*16
    float* pcnt = psum + (size_t)N_GRAPHS * 16;        // 256
    int*   deg    = (int*)(pcnt + N_GRAPHS);           // N
    int*   rowptr = deg + N_NODES;                     // N
    int*   pos    = rowptr + N_NODES;                  // N (row end after fill)
    int*   bsum   = pos + N_NODES;                     // 128
    int*   elist  = bsum + 128;                        // E

    // ---- CSR build (per call, deterministic set) ----
    hipMemsetAsync(deg, 0, sizeof(int) * N_NODES, stream);
    k_count<<<(N_EDGES + 255) / 256, 256, 0, stream>>>(dst, deg);
    k_scan_local<<<N_SCAN_BLOCKS, 256, 0, stream>>>(deg, rowptr, bsum);
    k_scan_bsum<<<1, 128, 0, stream>>>(bsum);
    k_scan_apply<<<(N_NODES + 255) / 256, 256, 0, stream>>>(rowptr, bsum, pos);
    k_fill<<<(N_EDGES + 255) / 256, 256, 0, stream>>>(src, dst, pos, elist);

    // ---- Layer 0: gather raw x (38-dim), then fused double-linear ----
    k_gather<38><<<(N_NODES * 38 + 255) / 256, 256, 0, stream>>>(x, rowptr, pos, elist, agg);
    k_update0<<<(N_NODES * 64 + 255) / 256, 256, 0, stream>>>(agg, x, Wrel0, b0, Wroot0, h1);

    // ---- Layer 1: transform first (64->32), gather 32-dim ----
    k_linear<64, 32><<<(N_NODES * 32 + 255) / 256, 256, 0, stream>>>(h1, Wrel1, y);
    k_gather<32><<<(N_NODES * 32 + 255) / 256, 256, 0, stream>>>(y, rowptr, pos, elist, agg);
    k_update_mid<64, 32><<<(N_NODES * 32 + 255) / 256, 256, 0, stream>>>(agg, h1, Wroot1, b1, h2);

    // ---- Layer 2: transform first (32->16), gather 16-dim, fused pool ----
    k_linear<32, 16><<<(N_NODES * 16 + 255) / 256, 256, 0, stream>>>(h2, Wrel2, y);
    k_gather<16><<<(N_NODES * 16 + 255) / 256, 256, 0, stream>>>(y, rowptr, pos, elist, agg);
    hipMemsetAsync(psum, 0, sizeof(float) * (N_GRAPHS * 16 + N_GRAPHS), stream);
    k_update2_pool<<<(N_NODES + 15) / 16, 256, 0, stream>>>(agg, h2, Wroot2, b2, batch, psum, pcnt);

    k_finalize<<<(N_GRAPHS * 16 + 255) / 256, 256, 0, stream>>>(psum, pcnt, out);
}

// Round 3
// 727.657 us; speedup vs baseline: 2.0624x; 1.4715x over previous
//
#include <hip/hip_runtime.h>
#include <math.h>

#define N_NODES  100000
#define N_EDGES  3200000
#define N_GRAPHS 256

// DIMS = [38, 64, 32, 16]

#define BSHIFT 8
#define NB ((N_NODES + 255) >> 8)                 // 391 buckets of 256 nodes
#define NBLK 640
#define EPB ((N_EDGES + NBLK - 1) / NBLK)         // 5000 edges per block

__device__ __forceinline__ float fast_tanh(float x) {
    x = fminf(20.f, fmaxf(-20.f, x));
    float e = __expf(2.f * x);
    return (e - 1.f) / (e + 1.f);
}

// ---------------- CSR build: two-level counting sort, LDS atomics only ----------------

// Pass A: per-block LDS histogram over buckets; reserve global ranges.
__global__ __launch_bounds__(256) void k_hist(const int* __restrict__ dst,
                                              int* __restrict__ bucket_cnt,
                                              int* __restrict__ blockoff) {
    __shared__ int hist[NB];
    int tid = threadIdx.x;
    int b = blockIdx.x;
    for (int i = tid; i < NB; i += 256) hist[i] = 0;
    __syncthreads();
    int lo = b * EPB;
    int hi = min(lo + EPB, N_EDGES);
    for (int e = lo + tid; e < hi; e += 256)
        atomicAdd(&hist[dst[e] >> BSHIFT], 1);
    __syncthreads();
    for (int i = tid; i < NB; i += 256) {
        int c = hist[i];
        blockoff[b * NB + i] = (c > 0) ? atomicAdd(&bucket_cnt[i], c) : 0;
    }
}

// exclusive scan of the 391 bucket counts (single block); also writes total at [NB]
__global__ __launch_bounds__(512) void k_scan_buckets(const int* __restrict__ bucket_cnt,
                                                      int* __restrict__ bucket_base) {
    __shared__ int sd[512];
    int tid = threadIdx.x;
    int v = (tid < NB) ? bucket_cnt[tid] : 0;
    int val = v;
    sd[tid] = val;
    __syncthreads();
#pragma unroll
    for (int off = 1; off < 512; off <<= 1) {
        int t = (tid >= off) ? sd[tid - off] : 0;
        __syncthreads();
        val += t;
        sd[tid] = val;
        __syncthreads();
    }
    if (tid < NB) {
        bucket_base[tid] = val - v;
        if (tid == NB - 1) bucket_base[NB] = val;
    }
}

// Pass B: scatter packed edges (src | dst_local<<17) into bucket-sorted order.
__global__ __launch_bounds__(256) void k_scatter_buckets(const int* __restrict__ src,
                                                         const int* __restrict__ dst,
                                                         const int* __restrict__ bucket_base,
                                                         const int* __restrict__ blockoff,
                                                         int* __restrict__ ebuf) {
    __shared__ int base[NB];
    __shared__ int cur[NB];
    int tid = threadIdx.x;
    int b = blockIdx.x;
    for (int i = tid; i < NB; i += 256) {
        base[i] = bucket_base[i] + blockoff[b * NB + i];
        cur[i] = 0;
    }
    __syncthreads();
    int lo = b * EPB;
    int hi = min(lo + EPB, N_EDGES);
    for (int e = lo + tid; e < hi; e += 256) {
        int d = dst[e];
        int bin = d >> BSHIFT;
        int r = atomicAdd(&cur[bin], 1);
        ebuf[base[bin] + r] = src[e] | ((d & 255) << 17);
    }
}

// Pass C: per-bucket node-level CSR (counts + scan + scatter, all in LDS / L2-local window)
__global__ __launch_bounds__(256) void k_bucket_csr(const int* __restrict__ ebuf,
                                                    const int* __restrict__ bucket_base,
                                                    int* __restrict__ rowptr,
                                                    int* __restrict__ rowend,
                                                    int* __restrict__ elist) {
    __shared__ int cnt[256];
    __shared__ int nb[256];
    __shared__ int cur[256];
    __shared__ int sscan[256];
    int b = blockIdx.x;
    int tid = threadIdx.x;
    int e0 = bucket_base[b];
    int e1 = bucket_base[b + 1];
    cnt[tid] = 0;
    cur[tid] = 0;
    __syncthreads();
    for (int j = e0 + tid; j < e1; j += 256)
        atomicAdd(&cnt[ebuf[j] >> 17], 1);
    __syncthreads();
    int v = cnt[tid];
    int val = v;
    sscan[tid] = val;
    __syncthreads();
#pragma unroll
    for (int off = 1; off < 256; off <<= 1) {
        int t = (tid >= off) ? sscan[tid - off] : 0;
        __syncthreads();
        val += t;
        sscan[tid] = val;
        __syncthreads();
    }
    int excl = val - v;
    nb[tid] = excl;
    int node = (b << BSHIFT) + tid;
    if (node < N_NODES) {
        rowptr[node] = e0 + excl;
        rowend[node] = e0 + val;
    }
    __syncthreads();
    for (int j = e0 + tid; j < e1; j += 256) {
        int w = ebuf[j];
        int dl = w >> 17;
        int r = atomicAdd(&cur[dl], 1);
        elist[e0 + nb[dl] + r] = w & 0x1FFFF;
    }
}

// ---------------- gather aggregation: agg[n][d] = sum_{j in in(n)} feat[elist[j]][d] ----------------
template<int DIM>
__global__ __launch_bounds__(256) void k_gather(const float* __restrict__ feat,
                                                const int* __restrict__ rowptr,
                                                const int* __restrict__ rowend,
                                                const int* __restrict__ elist,
                                                float* __restrict__ agg) {
    int idx = blockIdx.x * 256 + threadIdx.x;
    if (idx >= N_NODES * DIM) return;
    int n = idx / DIM;
    int d = idx - n * DIM;
    int j = rowptr[n];
    int e = rowend[n];
    float acc = 0.f;
    for (; j + 1 < e; j += 2) {
        int s0 = elist[j];
        int s1 = elist[j + 1];
        acc += feat[s0 * DIM + d];
        acc += feat[s1 * DIM + d];
    }
    if (j < e) acc += feat[elist[j] * DIM + d];
    agg[idx] = acc;
}

// -------- layer0 update: h1 = tanh(agg@Wrel^T + b + x@Wroot^T), 38 -> 64 --------
__global__ __launch_bounds__(256) void k_update0(const float* __restrict__ agg,
                                                 const float* __restrict__ x,
                                                 const float* __restrict__ Wrel,
                                                 const float* __restrict__ b,
                                                 const float* __restrict__ Wroot,
                                                 float* __restrict__ h1) {
    __shared__ float sWrel[64 * 38];
    __shared__ float sWroot[64 * 38];
    __shared__ float sb[64];
    for (int i = threadIdx.x; i < 64 * 38; i += 256) { sWrel[i] = Wrel[i]; sWroot[i] = Wroot[i]; }
    if (threadIdx.x < 64) sb[threadIdx.x] = b[threadIdx.x];
    __syncthreads();

    int idx = blockIdx.x * 256 + threadIdx.x;           // (n, o) o in [0,64)
    int n = idx >> 6;
    int o = idx & 63;
    if (n >= N_NODES) return;
    const float* ar = agg + n * 38;
    const float* xr = x   + n * 38;
    float acc = sb[o];
#pragma unroll
    for (int d = 0; d < 38; ++d)
        acc += ar[d] * sWrel[o * 38 + d] + xr[d] * sWroot[o * 38 + d];
    h1[idx] = fast_tanh(acc);
}

// -------- plain linear: out = in @ W^T  (no bias) --------
template<int DIN, int DOUT>
__global__ __launch_bounds__(256) void k_linear(const float* __restrict__ in,
                                                const float* __restrict__ W,
                                                float* __restrict__ out) {
    __shared__ float sW[DOUT * DIN];
    for (int i = threadIdx.x; i < DOUT * DIN; i += 256) sW[i] = W[i];
    __syncthreads();
    int idx = blockIdx.x * 256 + threadIdx.x;           // (n, o)
    int n = idx / DOUT;
    int o = idx - n * DOUT;
    if (n >= N_NODES) return;
    const float* r = in + n * DIN;
    float acc = 0.f;
#pragma unroll
    for (int k = 0; k < DIN; ++k) acc += r[k] * sW[o * DIN + k];
    out[idx] = acc;
}

// -------- mid update: h = tanh(agg + b + hin@Wroot^T) --------
template<int DIN, int DOUT>
__global__ __launch_bounds__(256) void k_update_mid(const float* __restrict__ agg,
                                                    const float* __restrict__ hin,
                                                    const float* __restrict__ Wroot,
                                                    const float* __restrict__ b,
                                                    float* __restrict__ out) {
    __shared__ float sW[DOUT * DIN];
    __shared__ float sb[DOUT];
    for (int i = threadIdx.x; i < DOUT * DIN; i += 256) sW[i] = Wroot[i];
    if (threadIdx.x < DOUT) sb[threadIdx.x] = b[threadIdx.x];
    __syncthreads();
    int idx = blockIdx.x * 256 + threadIdx.x;           // (n, o)
    int n = idx / DOUT;
    int o = idx - n * DOUT;
    if (n >= N_NODES) return;
    const float* r = hin + n * DIN;
    float acc = agg[idx] + sb[o];
#pragma unroll
    for (int k = 0; k < DIN; ++k) acc += r[k] * sW[o * DIN + k];
    out[idx] = fast_tanh(acc);
}

// -------- final update + fused mean-pool accumulation --------
__global__ __launch_bounds__(256) void k_update2_pool(const float* __restrict__ agg,
                                                      const float* __restrict__ h2,
                                                      const float* __restrict__ Wroot,
                                                      const float* __restrict__ b,
                                                      const int* __restrict__ batch,
                                                      float* __restrict__ psum,
                                                      float* __restrict__ pcnt) {
    __shared__ float sW[16 * 32];
    __shared__ float sb[16];
    __shared__ float slot[16][16];   // 16 graph slots x 16 dims
    __shared__ float scnt[16];
    __shared__ int sgmin;
    int tid = threadIdx.x;
    for (int i = tid; i < 16 * 32; i += 256) sW[i] = Wroot[i];
    if (tid < 16) { sb[tid] = b[tid]; scnt[tid] = 0.f; }
    ((float*)slot)[tid] = 0.f;       // exactly 256 entries
    int n0 = blockIdx.x * 16;
    if (tid == 0) sgmin = batch[n0];
    __syncthreads();

    int n = n0 + (tid >> 4);
    int o = tid & 15;
    if (n < N_NODES) {
        int g = batch[n];
        const float* r = h2 + n * 32;
        float acc = agg[n * 16 + o] + sb[o];
#pragma unroll
        for (int k = 0; k < 32; ++k) acc += r[k] * sW[o * 32 + k];
        int rel = g - sgmin;
        if (rel < 16) {
            atomicAdd(&slot[rel][o], acc);
            if (o == 0) atomicAdd(&scnt[rel], 1.f);
        } else {
            unsafeAtomicAdd(&psum[g * 16 + o], acc);
            if (o == 0) unsafeAtomicAdd(&pcnt[g], 1.f);
        }
    }
    __syncthreads();

    int s = tid >> 4;                 // 0..15
    int g = sgmin + s;
    if (g < N_GRAPHS) {
        unsafeAtomicAdd(&psum[g * 16 + o], slot[s][o]);
        if (o == 0) unsafeAtomicAdd(&pcnt[g], scnt[s]);
    }
}

__global__ __launch_bounds__(256) void k_finalize(const float* __restrict__ psum,
                                                  const float* __restrict__ pcnt,
                                                  float* __restrict__ out) {
    int idx = blockIdx.x * 256 + threadIdx.x;
    if (idx >= N_GRAPHS * 16) return;
    int g = idx >> 4;
    out[idx] = fast_tanh(psum[idx] / fmaxf(pcnt[g], 1.f));
}

extern "C" void kernel_launch(void* const* d_in, const int* in_sizes, int n_in,
                              void* d_out, int out_size, void* d_ws, size_t ws_size,
                              hipStream_t stream) {
    const float* x      = (const float*)d_in[0];
    const int*   eidx   = (const int*)d_in[1];
    const int*   src    = eidx;
    const int*   dst    = eidx + N_EDGES;
    const int*   batch  = (const int*)d_in[2];
    const float* Wrel0  = (const float*)d_in[3];
    const float* b0     = (const float*)d_in[4];
    const float* Wroot0 = (const float*)d_in[5];
    const float* Wrel1  = (const float*)d_in[6];
    const float* b1     = (const float*)d_in[7];
    const float* Wroot1 = (const float*)d_in[8];
    const float* Wrel2  = (const float*)d_in[9];
    const float* b2     = (const float*)d_in[10];
    const float* Wroot2 = (const float*)d_in[11];
    float* out = (float*)d_out;

    // ---- workspace layout ----
    float* ws   = (float*)d_ws;
    float* agg  = ws;                                  // N*38 (reused 38/32/16)
    float* h1   = agg + (size_t)N_NODES * 38;          // N*64
    float* y    = h1  + (size_t)N_NODES * 64;          // N*32 max
    float* h2   = y   + (size_t)N_NODES * 32;          // N*32  (== E words; aliased as ebuf during CSR build)
    float* psum = h2  + (size_t)N_NODES * 32;          // 256*16
    float* pcnt = psum + (size_t)N_GRAPHS * 16;        // 256
    int* rowptr      = (int*)(pcnt + N_GRAPHS);        // N
    int* rowend      = rowptr + N_NODES;               // N
    int* bucket_cnt  = rowend + N_NODES;               // NB (pad 400)
    int* bucket_base = bucket_cnt + 400;               // NB+1 (pad 400)
    int* blockoff    = bucket_base + 400;              // NBLK*NB
    int* elist       = blockoff + NBLK * NB;           // E
    int* ebuf        = (int*)h2;                       // E (alias; dead before h2 is written)

    // ---- CSR build (bucketed counting sort; all fine-grained atomics in LDS) ----
    hipMemsetAsync(bucket_cnt, 0, sizeof(int) * NB, stream);
    k_hist<<<NBLK, 256, 0, stream>>>(dst, bucket_cnt, blockoff);
    k_scan_buckets<<<1, 512, 0, stream>>>(bucket_cnt, bucket_base);
    k_scatter_buckets<<<NBLK, 256, 0, stream>>>(src, dst, bucket_base, blockoff, ebuf);
    k_bucket_csr<<<NB, 256, 0, stream>>>(ebuf, bucket_base, rowptr, rowend, elist);

    // ---- Layer 0: gather raw x (38-dim), then fused double-linear ----
    k_gather<38><<<(N_NODES * 38 + 255) / 256, 256, 0, stream>>>(x, rowptr, rowend, elist, agg);
    k_update0<<<(N_NODES * 64 + 255) / 256, 256, 0, stream>>>(agg, x, Wrel0, b0, Wroot0, h1);

    // ---- Layer 1: transform first (64->32), gather 32-dim ----
    k_linear<64, 32><<<(N_NODES * 32 + 255) / 256, 256, 0, stream>>>(h1, Wrel1, y);
    k_gather<32><<<(N_NODES * 32 + 255) / 256, 256, 0, stream>>>(y, rowptr, rowend, elist, agg);
    k_update_mid<64, 32><<<(N_NODES * 32 + 255) / 256, 256, 0, stream>>>(agg, h1, Wroot1, b1, h2);

    // ---- Layer 2: transform first (32->16), gather 16-dim, fused pool ----
    k_linear<32, 16><<<(N_NODES * 16 + 255) / 256, 256, 0, stream>>>(h2, Wrel2, y);
    k_gather<16><<<(N_NODES * 16 + 255) / 256, 256, 0, stream>>>(y, rowptr, rowend, elist, agg);
    hipMemsetAsync(psum, 0, sizeof(float) * (N_GRAPHS * 16 + N_GRAPHS), stream);
    k_update2_pool<<<(N_NODES + 15) / 16, 256, 0, stream>>>(agg, h2, Wroot2, b2, batch, psum, pcnt);

    k_finalize<<<(N_GRAPHS * 16 + 255) / 256, 256, 0, stream>>>(psum, pcnt, out);
}

// Round 4
// 591.378 us; speedup vs baseline: 2.5377x; 1.2304x over previous
//
#include <hip/hip_runtime.h>
#include <math.h>

#define N_NODES  100000
#define N_EDGES  3200000
#define N_GRAPHS 256

// DIMS = [38, 64, 32, 16]

#define BSHIFT 8
#define NB ((N_NODES + 255) >> 8)                 // 391 buckets of 256 nodes
#define NBLK 640
#define EPB ((N_EDGES + NBLK - 1) / NBLK)         // 5000 edges per block

__device__ __forceinline__ float fast_tanh(float x) {
    x = fminf(20.f, fmaxf(-20.f, x));
    float e = __expf(2.f * x);
    return (e - 1.f) / (e + 1.f);
}

// pack two f32 -> bf16x2 (RNE)
__device__ __forceinline__ unsigned int pack_bf2(float a, float b) {
    unsigned int ua = __float_as_uint(a);
    unsigned int ub = __float_as_uint(b);
    ua += 0x7fffu + ((ua >> 16) & 1u);
    ub += 0x7fffu + ((ub >> 16) & 1u);
    return (ua >> 16) | (ub & 0xffff0000u);
}
__device__ __forceinline__ unsigned short f2bf(float a) {
    unsigned int ua = __float_as_uint(a);
    ua += 0x7fffu + ((ua >> 16) & 1u);
    return (unsigned short)(ua >> 16);
}

// ---------------- CSR build: two-level counting sort, LDS atomics only ----------------

__global__ __launch_bounds__(256) void k_hist(const int* __restrict__ dst,
                                              int* __restrict__ bucket_cnt,
                                              int* __restrict__ blockoff) {
    __shared__ int hist[NB];
    int tid = threadIdx.x;
    int b = blockIdx.x;
    for (int i = tid; i < NB; i += 256) hist[i] = 0;
    __syncthreads();
    int lo = b * EPB;
    int hi = min(lo + EPB, N_EDGES);
    for (int e = lo + tid; e < hi; e += 256)
        atomicAdd(&hist[dst[e] >> BSHIFT], 1);
    __syncthreads();
    for (int i = tid; i < NB; i += 256) {
        int c = hist[i];
        blockoff[b * NB + i] = (c > 0) ? atomicAdd(&bucket_cnt[i], c) : 0;
    }
}

__global__ __launch_bounds__(512) void k_scan_buckets(const int* __restrict__ bucket_cnt,
                                                      int* __restrict__ bucket_base) {
    __shared__ int sd[512];
    int tid = threadIdx.x;
    int v = (tid < NB) ? bucket_cnt[tid] : 0;
    int val = v;
    sd[tid] = val;
    __syncthreads();
#pragma unroll
    for (int off = 1; off < 512; off <<= 1) {
        int t = (tid >= off) ? sd[tid - off] : 0;
        __syncthreads();
        val += t;
        sd[tid] = val;
        __syncthreads();
    }
    if (tid < NB) {
        bucket_base[tid] = val - v;
        if (tid == NB - 1) bucket_base[NB] = val;
    }
}

__global__ __launch_bounds__(256) void k_scatter_buckets(const int* __restrict__ src,
                                                         const int* __restrict__ dst,
                                                         const int* __restrict__ bucket_base,
                                                         const int* __restrict__ blockoff,
                                                         int* __restrict__ ebuf) {
    __shared__ int base[NB];
    __shared__ int cur[NB];
    int tid = threadIdx.x;
    int b = blockIdx.x;
    for (int i = tid; i < NB; i += 256) {
        base[i] = bucket_base[i] + blockoff[b * NB + i];
        cur[i] = 0;
    }
    __syncthreads();
    int lo = b * EPB;
    int hi = min(lo + EPB, N_EDGES);
    for (int e = lo + tid; e < hi; e += 256) {
        int d = dst[e];
        int bin = d >> BSHIFT;
        int r = atomicAdd(&cur[bin], 1);
        ebuf[base[bin] + r] = src[e] | ((d & 255) << 17);
    }
}

__global__ __launch_bounds__(256) void k_bucket_csr(const int* __restrict__ ebuf,
                                                    const int* __restrict__ bucket_base,
                                                    int* __restrict__ rowptr,
                                                    int* __restrict__ rowend,
                                                    int* __restrict__ elist) {
    __shared__ int cnt[256];
    __shared__ int nb[256];
    __shared__ int cur[256];
    __shared__ int sscan[256];
    int b = blockIdx.x;
    int tid = threadIdx.x;
    int e0 = bucket_base[b];
    int e1 = bucket_base[b + 1];
    cnt[tid] = 0;
    cur[tid] = 0;
    __syncthreads();
    for (int j = e0 + tid; j < e1; j += 256)
        atomicAdd(&cnt[ebuf[j] >> 17], 1);
    __syncthreads();
    int v = cnt[tid];
    int val = v;
    sscan[tid] = val;
    __syncthreads();
#pragma unroll
    for (int off = 1; off < 256; off <<= 1) {
        int t = (tid >= off) ? sscan[tid - off] : 0;
        __syncthreads();
        val += t;
        sscan[tid] = val;
        __syncthreads();
    }
    int excl = val - v;
    nb[tid] = excl;
    int node = (b << BSHIFT) + tid;
    if (node < N_NODES) {
        rowptr[node] = e0 + excl;
        rowend[node] = e0 + val;
    }
    __syncthreads();
    for (int j = e0 + tid; j < e1; j += 256) {
        int w = ebuf[j];
        int dl = w >> 17;
        int r = atomicAdd(&cur[dl], 1);
        elist[e0 + nb[dl] + r] = w & 0x1FFFF;
    }
}

// ---------------- cast f32 -> packed bf16 pairs ----------------
__global__ __launch_bounds__(256) void k_cast_bf16(const float* __restrict__ in,
                                                   unsigned int* __restrict__ out,
                                                   int n_pairs) {
    int i = blockIdx.x * 256 + threadIdx.x;
    if (i >= n_pairs) return;
    float2 v = ((const float2*)in)[i];
    out[i] = pack_bf2(v.x, v.y);
}

// ---------------- gather (bf16 pairs): agg[n][2p..2p+1] = sum feat[elist[j]][pair p] ----------------
template<int DIM2>
__global__ __launch_bounds__(256) void k_gather_bf16(const unsigned int* __restrict__ feat,
                                                     const int* __restrict__ rowptr,
                                                     const int* __restrict__ rowend,
                                                     const int* __restrict__ elist,
                                                     float* __restrict__ agg) {
    int idx = blockIdx.x * 256 + threadIdx.x;
    if (idx >= N_NODES * DIM2) return;
    int n = idx / DIM2;
    int p = idx - n * DIM2;
    int j = rowptr[n];
    int e = rowend[n];
    float a0 = 0.f, a1 = 0.f;
    for (; j + 3 < e; j += 4) {
        int s0 = elist[j];
        int s1 = elist[j + 1];
        int s2 = elist[j + 2];
        int s3 = elist[j + 3];
        unsigned int w0 = feat[s0 * DIM2 + p];
        unsigned int w1 = feat[s1 * DIM2 + p];
        unsigned int w2 = feat[s2 * DIM2 + p];
        unsigned int w3 = feat[s3 * DIM2 + p];
        a0 += __uint_as_float(w0 << 16);
        a1 += __uint_as_float(w0 & 0xffff0000u);
        a0 += __uint_as_float(w1 << 16);
        a1 += __uint_as_float(w1 & 0xffff0000u);
        a0 += __uint_as_float(w2 << 16);
        a1 += __uint_as_float(w2 & 0xffff0000u);
        a0 += __uint_as_float(w3 << 16);
        a1 += __uint_as_float(w3 & 0xffff0000u);
    }
    for (; j < e; ++j) {
        unsigned int w = feat[elist[j] * DIM2 + p];
        a0 += __uint_as_float(w << 16);
        a1 += __uint_as_float(w & 0xffff0000u);
    }
    agg[n * (2 * DIM2) + 2 * p]     = a0;
    agg[n * (2 * DIM2) + 2 * p + 1] = a1;
}

// -------- layer0 update: h1 = tanh(agg@Wrel^T + b + x@Wroot^T), 38 -> 64 --------
__global__ __launch_bounds__(256) void k_update0(const float* __restrict__ agg,
                                                 const float* __restrict__ x,
                                                 const float* __restrict__ Wrel,
                                                 const float* __restrict__ b,
                                                 const float* __restrict__ Wroot,
                                                 float* __restrict__ h1) {
    __shared__ float sWrel[64 * 38];
    __shared__ float sWroot[64 * 38];
    __shared__ float sb[64];
    for (int i = threadIdx.x; i < 64 * 38; i += 256) { sWrel[i] = Wrel[i]; sWroot[i] = Wroot[i]; }
    if (threadIdx.x < 64) sb[threadIdx.x] = b[threadIdx.x];
    __syncthreads();

    int idx = blockIdx.x * 256 + threadIdx.x;           // (n, o) o in [0,64)
    int n = idx >> 6;
    int o = idx & 63;
    if (n >= N_NODES) return;
    const float* ar = agg + n * 38;
    const float* xr = x   + n * 38;
    float acc = sb[o];
#pragma unroll
    for (int d = 0; d < 38; ++d)
        acc += ar[d] * sWrel[o * 38 + d] + xr[d] * sWroot[o * 38 + d];
    h1[idx] = fast_tanh(acc);
}

// -------- linear with bf16 output: out_bf[n][o] = (bf16) in[n][:]@W[o][:] --------
template<int DIN, int DOUT>
__global__ __launch_bounds__(256) void k_linear_bf16(const float* __restrict__ in,
                                                     const float* __restrict__ W,
                                                     unsigned short* __restrict__ out) {
    __shared__ float sW[DOUT * DIN];
    for (int i = threadIdx.x; i < DOUT * DIN; i += 256) sW[i] = W[i];
    __syncthreads();
    int idx = blockIdx.x * 256 + threadIdx.x;           // (n, o)
    int n = idx / DOUT;
    int o = idx - n * DOUT;
    if (n >= N_NODES) return;
    const float* r = in + n * DIN;
    float acc = 0.f;
#pragma unroll
    for (int k = 0; k < DIN; ++k) acc += r[k] * sW[o * DIN + k];
    out[idx] = f2bf(acc);
}

// -------- mid update: h = tanh(agg + b + hin@Wroot^T) --------
template<int DIN, int DOUT>
__global__ __launch_bounds__(256) void k_update_mid(const float* __restrict__ agg,
                                                    const float* __restrict__ hin,
                                                    const float* __restrict__ Wroot,
                                                    const float* __restrict__ b,
                                                    float* __restrict__ out) {
    __shared__ float sW[DOUT * DIN];
    __shared__ float sb[DOUT];
    for (int i = threadIdx.x; i < DOUT * DIN; i += 256) sW[i] = Wroot[i];
    if (threadIdx.x < DOUT) sb[threadIdx.x] = b[threadIdx.x];
    __syncthreads();
    int idx = blockIdx.x * 256 + threadIdx.x;           // (n, o)
    int n = idx / DOUT;
    int o = idx - n * DOUT;
    if (n >= N_NODES) return;
    const float* r = hin + n * DIN;
    float acc = agg[idx] + sb[o];
#pragma unroll
    for (int k = 0; k < DIN; ++k) acc += r[k] * sW[o * DIN + k];
    out[idx] = fast_tanh(acc);
}

// -------- final update + fused mean-pool accumulation --------
__global__ __launch_bounds__(256) void k_update2_pool(const float* __restrict__ agg,
                                                      const float* __restrict__ h2,
                                                      const float* __restrict__ Wroot,
                                                      const float* __restrict__ b,
                                                      const int* __restrict__ batch,
                                                      float* __restrict__ psum,
                                                      float* __restrict__ pcnt) {
    __shared__ float sW[16 * 32];
    __shared__ float sb[16];
    __shared__ float slot[16][16];
    __shared__ float scnt[16];
    __shared__ int sgmin;
    int tid = threadIdx.x;
    for (int i = tid; i < 16 * 32; i += 256) sW[i] = Wroot[i];
    if (tid < 16) { sb[tid] = b[tid]; scnt[tid] = 0.f; }
    ((float*)slot)[tid] = 0.f;
    int n0 = blockIdx.x * 16;
    if (tid == 0) sgmin = batch[n0];
    __syncthreads();

    int n = n0 + (tid >> 4);
    int o = tid & 15;
    if (n < N_NODES) {
        int g = batch[n];
        const float* r = h2 + n * 32;
        float acc = agg[n * 16 + o] + sb[o];
#pragma unroll
        for (int k = 0; k < 32; ++k) acc += r[k] * sW[o * 32 + k];
        int rel = g - sgmin;
        if (rel < 16) {
            atomicAdd(&slot[rel][o], acc);
            if (o == 0) atomicAdd(&scnt[rel], 1.f);
        } else {
            unsafeAtomicAdd(&psum[g * 16 + o], acc);
            if (o == 0) unsafeAtomicAdd(&pcnt[g], 1.f);
        }
    }
    __syncthreads();

    int s = tid >> 4;
    int g = sgmin + s;
    if (g < N_GRAPHS) {
        unsafeAtomicAdd(&psum[g * 16 + o], slot[s][o]);
        if (o == 0) unsafeAtomicAdd(&pcnt[g], scnt[s]);
    }
}

__global__ __launch_bounds__(256) void k_finalize(const float* __restrict__ psum,
                                                  const float* __restrict__ pcnt,
                                                  float* __restrict__ out) {
    int idx = blockIdx.x * 256 + threadIdx.x;
    if (idx >= N_GRAPHS * 16) return;
    int g = idx >> 4;
    out[idx] = fast_tanh(psum[idx] / fmaxf(pcnt[g], 1.f));
}

extern "C" void kernel_launch(void* const* d_in, const int* in_sizes, int n_in,
                              void* d_out, int out_size, void* d_ws, size_t ws_size,
                              hipStream_t stream) {
    const float* x      = (const float*)d_in[0];
    const int*   eidx   = (const int*)d_in[1];
    const int*   src    = eidx;
    const int*   dst    = eidx + N_EDGES;
    const int*   batch  = (const int*)d_in[2];
    const float* Wrel0  = (const float*)d_in[3];
    const float* b0     = (const float*)d_in[4];
    const float* Wroot0 = (const float*)d_in[5];
    const float* Wrel1  = (const float*)d_in[6];
    const float* b1     = (const float*)d_in[7];
    const float* Wroot1 = (const float*)d_in[8];
    const float* Wrel2  = (const float*)d_in[9];
    const float* b2     = (const float*)d_in[10];
    const float* Wroot2 = (const float*)d_in[11];
    float* out = (float*)d_out;

    // ---- workspace layout ----
    float* ws   = (float*)d_ws;
    float* agg  = ws;                                  // N*38 f32 (reused 38/32/16)
    float* h1   = agg + (size_t)N_NODES * 38;          // N*64 f32
    float* y    = h1  + (size_t)N_NODES * 64;          // bf16 y buffers live here
    float* h2   = y   + (size_t)N_NODES * 32;          // N*32 f32 (aliased as ebuf during CSR build)
    float* psum = h2  + (size_t)N_NODES * 32;          // 256*16
    float* pcnt = psum + (size_t)N_GRAPHS * 16;        // 256
    int* rowptr      = (int*)(pcnt + N_GRAPHS);        // N
    int* rowend      = rowptr + N_NODES;               // N
    int* bucket_cnt  = rowend + N_NODES;               // NB (pad 400)
    int* bucket_base = bucket_cnt + 400;               // NB+1 (pad 400)
    int* blockoff    = bucket_base + 400;              // NBLK*NB
    int* elist       = blockoff + NBLK * NB;           // E
    int* ebuf        = (int*)h2;                       // E (alias; dead before h2 is written)
    unsigned int* xb = (unsigned int*)h1;              // N*19 pairs (alias; dead before h1 is written)
    unsigned int* yb = (unsigned int*)y;               // N*16 / N*8 pairs

    // ---- cast x to bf16 pairs (dead after layer-0 gather; aliases h1) ----
    k_cast_bf16<<<(N_NODES * 19 + 255) / 256, 256, 0, stream>>>(x, xb, N_NODES * 19);

    // ---- CSR build (bucketed counting sort; all fine-grained atomics in LDS) ----
    hipMemsetAsync(bucket_cnt, 0, sizeof(int) * NB, stream);
    k_hist<<<NBLK, 256, 0, stream>>>(dst, bucket_cnt, blockoff);
    k_scan_buckets<<<1, 512, 0, stream>>>(bucket_cnt, bucket_base);
    k_scatter_buckets<<<NBLK, 256, 0, stream>>>(src, dst, bucket_base, blockoff, ebuf);
    k_bucket_csr<<<NB, 256, 0, stream>>>(ebuf, bucket_base, rowptr, rowend, elist);

    // ---- Layer 0: gather bf16 x (19 pairs), then fused double-linear ----
    k_gather_bf16<19><<<(N_NODES * 19 + 255) / 256, 256, 0, stream>>>(xb, rowptr, rowend, elist, agg);
    k_update0<<<(N_NODES * 64 + 255) / 256, 256, 0, stream>>>(agg, x, Wrel0, b0, Wroot0, h1);

    // ---- Layer 1: transform first (64->32, bf16 out), gather 16 pairs ----
    k_linear_bf16<64, 32><<<(N_NODES * 32 + 255) / 256, 256, 0, stream>>>(h1, Wrel1, (unsigned short*)yb);
    k_gather_bf16<16><<<(N_NODES * 16 + 255) / 256, 256, 0, stream>>>(yb, rowptr, rowend, elist, agg);
    k_update_mid<64, 32><<<(N_NODES * 32 + 255) / 256, 256, 0, stream>>>(agg, h1, Wroot1, b1, h2);

    // ---- Layer 2: transform first (32->16, bf16 out), gather 8 pairs, fused pool ----
    k_linear_bf16<32, 16><<<(N_NODES * 16 + 255) / 256, 256, 0, stream>>>(h2, Wrel2, (unsigned short*)yb);
    k_gather_bf16<8><<<(N_NODES * 8 + 255) / 256, 256, 0, stream>>>(yb, rowptr, rowend, elist, agg);
    hipMemsetAsync(psum, 0, sizeof(float) * (N_GRAPHS * 16 + N_GRAPHS), stream);
    k_update2_pool<<<(N_NODES + 15) / 16, 256, 0, stream>>>(agg, h2, Wroot2, b2, batch, psum, pcnt);

    k_finalize<<<(N_GRAPHS * 16 + 255) / 256, 256, 0, stream>>>(psum, pcnt, out);
}

// Round 5
// 540.745 us; speedup vs baseline: 2.7753x; 1.0936x over previous
//
#include <hip/hip_runtime.h>
#include <math.h>

#define N_NODES  100000
#define N_EDGES  3200000
#define N_GRAPHS 256

// DIMS = [38, 64, 32, 16]

#define BSHIFT 8
#define NB ((N_NODES + 255) >> 8)                 // 391 buckets of 256 nodes
#define NBLK 640
#define EPB ((N_EDGES + NBLK - 1) / NBLK)         // 5000 edges per block

__device__ __forceinline__ float fast_tanh(float x) {
    x = fminf(20.f, fmaxf(-20.f, x));
    float e = __expf(2.f * x);
    return (e - 1.f) / (e + 1.f);
}

// pack two f32 -> bf16x2 (RNE)
__device__ __forceinline__ unsigned int pack_bf2(float a, float b) {
    unsigned int ua = __float_as_uint(a);
    unsigned int ub = __float_as_uint(b);
    ua += 0x7fffu + ((ua >> 16) & 1u);
    ub += 0x7fffu + ((ub >> 16) & 1u);
    return (ua >> 16) | (ub & 0xffff0000u);
}
__device__ __forceinline__ unsigned short f2bf(float a) {
    unsigned int ua = __float_as_uint(a);
    ua += 0x7fffu + ((ua >> 16) & 1u);
    return (unsigned short)(ua >> 16);
}

// ---------------- CSR build: two-level counting sort, LDS atomics only ----------------

__global__ __launch_bounds__(256) void k_hist(const int* __restrict__ dst,
                                              int* __restrict__ bucket_cnt,
                                              int* __restrict__ blockoff) {
    __shared__ int hist[NB];
    int tid = threadIdx.x;
    int b = blockIdx.x;
    for (int i = tid; i < NB; i += 256) hist[i] = 0;
    __syncthreads();
    int lo = b * EPB;
    int hi = min(lo + EPB, N_EDGES);
    for (int e = lo + tid; e < hi; e += 256)
        atomicAdd(&hist[dst[e] >> BSHIFT], 1);
    __syncthreads();
    for (int i = tid; i < NB; i += 256) {
        int c = hist[i];
        blockoff[b * NB + i] = (c > 0) ? atomicAdd(&bucket_cnt[i], c) : 0;
    }
}

__global__ __launch_bounds__(512) void k_scan_buckets(const int* __restrict__ bucket_cnt,
                                                      int* __restrict__ bucket_base) {
    __shared__ int sd[512];
    int tid = threadIdx.x;
    int v = (tid < NB) ? bucket_cnt[tid] : 0;
    int val = v;
    sd[tid] = val;
    __syncthreads();
#pragma unroll
    for (int off = 1; off < 512; off <<= 1) {
        int t = (tid >= off) ? sd[tid - off] : 0;
        __syncthreads();
        val += t;
        sd[tid] = val;
        __syncthreads();
    }
    if (tid < NB) {
        bucket_base[tid] = val - v;
        if (tid == NB - 1) bucket_base[NB] = val;
    }
}

__global__ __launch_bounds__(256) void k_scatter_buckets(const int* __restrict__ src,
                                                         const int* __restrict__ dst,
                                                         const int* __restrict__ bucket_base,
                                                         const int* __restrict__ blockoff,
                                                         int* __restrict__ ebuf) {
    __shared__ int base[NB];
    __shared__ int cur[NB];
    int tid = threadIdx.x;
    int b = blockIdx.x;
    for (int i = tid; i < NB; i += 256) {
        base[i] = bucket_base[i] + blockoff[b * NB + i];
        cur[i] = 0;
    }
    __syncthreads();
    int lo = b * EPB;
    int hi = min(lo + EPB, N_EDGES);
    for (int e = lo + tid; e < hi; e += 256) {
        int d = dst[e];
        int bin = d >> BSHIFT;
        int r = atomicAdd(&cur[bin], 1);
        ebuf[base[bin] + r] = src[e] | ((d & 255) << 17);
    }
}

__global__ __launch_bounds__(256) void k_bucket_csr(const int* __restrict__ ebuf,
                                                    const int* __restrict__ bucket_base,
                                                    int* __restrict__ rowptr,
                                                    int* __restrict__ rowend,
                                                    int* __restrict__ elist) {
    __shared__ int cnt[256];
    __shared__ int nb[256];
    __shared__ int cur[256];
    __shared__ int sscan[256];
    int b = blockIdx.x;
    int tid = threadIdx.x;
    int e0 = bucket_base[b];
    int e1 = bucket_base[b + 1];
    cnt[tid] = 0;
    cur[tid] = 0;
    __syncthreads();
    for (int j = e0 + tid; j < e1; j += 256)
        atomicAdd(&cnt[ebuf[j] >> 17], 1);
    __syncthreads();
    int v = cnt[tid];
    int val = v;
    sscan[tid] = val;
    __syncthreads();
#pragma unroll
    for (int off = 1; off < 256; off <<= 1) {
        int t = (tid >= off) ? sscan[tid - off] : 0;
        __syncthreads();
        val += t;
        sscan[tid] = val;
        __syncthreads();
    }
    int excl = val - v;
    nb[tid] = excl;
    int node = (b << BSHIFT) + tid;
    if (node < N_NODES) {
        rowptr[node] = e0 + excl;
        rowend[node] = e0 + val;
    }
    __syncthreads();
    for (int j = e0 + tid; j < e1; j += 256) {
        int w = ebuf[j];
        int dl = w >> 17;
        int r = atomicAdd(&cur[dl], 1);
        elist[e0 + nb[dl] + r] = w & 0x1FFFF;
    }
}

// ---------------- cast f32 -> packed bf16 pairs ----------------
__global__ __launch_bounds__(256) void k_cast_bf16(const float* __restrict__ in,
                                                   unsigned int* __restrict__ out,
                                                   int n_pairs) {
    int i = blockIdx.x * 256 + threadIdx.x;
    if (i >= n_pairs) return;
    float2 v = ((const float2*)in)[i];
    out[i] = pack_bf2(v.x, v.y);
}

// ---------------- gather (bf16 pairs): agg[n][2p..2p+1] = sum feat[elist[j]][pair p] ----------------
template<int DIM2>
__global__ __launch_bounds__(256) void k_gather_bf16(const unsigned int* __restrict__ feat,
                                                     const int* __restrict__ rowptr,
                                                     const int* __restrict__ rowend,
                                                     const int* __restrict__ elist,
                                                     float* __restrict__ agg) {
    int idx = blockIdx.x * 256 + threadIdx.x;
    if (idx >= N_NODES * DIM2) return;
    int n = idx / DIM2;
    int p = idx - n * DIM2;
    int j = rowptr[n];
    int e = rowend[n];
    float a0 = 0.f, a1 = 0.f;
    for (; j + 3 < e; j += 4) {
        int s0 = elist[j];
        int s1 = elist[j + 1];
        int s2 = elist[j + 2];
        int s3 = elist[j + 3];
        unsigned int w0 = feat[s0 * DIM2 + p];
        unsigned int w1 = feat[s1 * DIM2 + p];
        unsigned int w2 = feat[s2 * DIM2 + p];
        unsigned int w3 = feat[s3 * DIM2 + p];
        a0 += __uint_as_float(w0 << 16);
        a1 += __uint_as_float(w0 & 0xffff0000u);
        a0 += __uint_as_float(w1 << 16);
        a1 += __uint_as_float(w1 & 0xffff0000u);
        a0 += __uint_as_float(w2 << 16);
        a1 += __uint_as_float(w2 & 0xffff0000u);
        a0 += __uint_as_float(w3 << 16);
        a1 += __uint_as_float(w3 & 0xffff0000u);
    }
    for (; j < e; ++j) {
        unsigned int w = feat[elist[j] * DIM2 + p];
        a0 += __uint_as_float(w << 16);
        a1 += __uint_as_float(w & 0xffff0000u);
    }
    agg[n * (2 * DIM2) + 2 * p]     = a0;
    agg[n * (2 * DIM2) + 2 * p + 1] = a1;
}

// -------- layer0 update: h1 = tanh(agg@Wrel^T + b + x@Wroot^T), 38 -> 64 --------
__global__ __launch_bounds__(256) void k_update0(const float* __restrict__ agg,
                                                 const float* __restrict__ x,
                                                 const float* __restrict__ Wrel,
                                                 const float* __restrict__ b,
                                                 const float* __restrict__ Wroot,
                                                 float* __restrict__ h1) {
    __shared__ float sWrel[64 * 38];
    __shared__ float sWroot[64 * 38];
    __shared__ float sb[64];
    for (int i = threadIdx.x; i < 64 * 38; i += 256) { sWrel[i] = Wrel[i]; sWroot[i] = Wroot[i]; }
    if (threadIdx.x < 64) sb[threadIdx.x] = b[threadIdx.x];
    __syncthreads();

    int idx = blockIdx.x * 256 + threadIdx.x;           // (n, o) o in [0,64)
    int n = idx >> 6;
    int o = idx & 63;
    if (n >= N_NODES) return;
    const float* ar = agg + n * 38;
    const float* xr = x   + n * 38;
    float acc = sb[o];
#pragma unroll
    for (int d = 0; d < 38; ++d)
        acc += ar[d] * sWrel[o * 38 + d] + xr[d] * sWroot[o * 38 + d];
    h1[idx] = fast_tanh(acc);
}

// -------- linear with bf16 output: out_bf[n][o] = (bf16) in[n][:]@W[o][:] --------
template<int DIN, int DOUT>
__global__ __launch_bounds__(256) void k_linear_bf16(const float* __restrict__ in,
                                                     const float* __restrict__ W,
                                                     unsigned short* __restrict__ out) {
    __shared__ float sW[DOUT * DIN];
    for (int i = threadIdx.x; i < DOUT * DIN; i += 256) sW[i] = W[i];
    __syncthreads();
    int idx = blockIdx.x * 256 + threadIdx.x;           // (n, o)
    int n = idx / DOUT;
    int o = idx - n * DOUT;
    if (n >= N_NODES) return;
    const float* r = in + n * DIN;
    float acc = 0.f;
#pragma unroll
    for (int k = 0; k < DIN; ++k) acc += r[k] * sW[o * DIN + k];
    out[idx] = f2bf(acc);
}

// -------- mid update: h = tanh(agg + b + hin@Wroot^T) --------
template<int DIN, int DOUT>
__global__ __launch_bounds__(256) void k_update_mid(const float* __restrict__ agg,
                                                    const float* __restrict__ hin,
                                                    const float* __restrict__ Wroot,
                                                    const float* __restrict__ b,
                                                    float* __restrict__ out) {
    __shared__ float sW[DOUT * DIN];
    __shared__ float sb[DOUT];
    for (int i = threadIdx.x; i < DOUT * DIN; i += 256) sW[i] = Wroot[i];
    if (threadIdx.x < DOUT) sb[threadIdx.x] = b[threadIdx.x];
    __syncthreads();
    int idx = blockIdx.x * 256 + threadIdx.x;           // (n, o)
    int n = idx / DOUT;
    int o = idx - n * DOUT;
    if (n >= N_NODES) return;
    const float* r = hin + n * DIN;
    float acc = agg[idx] + sb[o];
#pragma unroll
    for (int k = 0; k < DIN; ++k) acc += r[k] * sW[o * DIN + k];
    out[idx] = fast_tanh(acc);
}

// -------- graph boundaries from sorted batch vector --------
__global__ __launch_bounds__(256) void k_graph_start(const int* __restrict__ batch,
                                                     int* __restrict__ gstart) {
    int i = blockIdx.x * 256 + threadIdx.x;
    if (i >= N_NODES) return;
    int g = batch[i];
    int gp = (i == 0) ? -1 : batch[i - 1];
    for (int gg = gp + 1; gg <= g; ++gg) gstart[gg] = i;
    if (i == N_NODES - 1)
        for (int gg = g + 1; gg <= N_GRAPHS; ++gg) gstart[gg] = N_NODES;
}

// -------- per-graph sums of agg[16] and h2[32], no atomics (batch sorted) --------
__global__ __launch_bounds__(256) void k_pool(const float* __restrict__ agg,   // [N][16]
                                              const float* __restrict__ h2,    // [N][32]
                                              const int* __restrict__ gstart,
                                              float* __restrict__ psum)        // [G][48]
{
    __shared__ float part[4][48];
    int g = blockIdx.x;
    int wave = threadIdx.x >> 6;
    int lane = threadIdx.x & 63;
    int s = gstart[g], e = gstart[g + 1];
    if (lane < 48) {
        float a0 = 0.f, a1 = 0.f;
        if (lane < 16) {
            int n = s + wave;
            for (; n + 4 < e; n += 8) {
                a0 += agg[n * 16 + lane];
                a1 += agg[(n + 4) * 16 + lane];
            }
            if (n < e) a0 += agg[n * 16 + lane];
        } else {
            int d = lane - 16;
            int n = s + wave;
            for (; n + 4 < e; n += 8) {
                a0 += h2[n * 32 + d];
                a1 += h2[(n + 4) * 32 + d];
            }
            if (n < e) a0 += h2[n * 32 + d];
        }
        part[wave][lane] = a0 + a1;
    }
    __syncthreads();
    if (threadIdx.x < 48)
        psum[g * 48 + threadIdx.x] = part[0][threadIdx.x] + part[1][threadIdx.x]
                                   + part[2][threadIdx.x] + part[3][threadIdx.x];
}

// -------- finalize: out[g][o] = tanh((psum16[o] + cnt*b[o] + psum32 . W[o]) / cnt) --------
__global__ __launch_bounds__(256) void k_finalize2(const float* __restrict__ psum,  // [G][48]
                                                   const float* __restrict__ Wroot, // [16][32]
                                                   const float* __restrict__ b,
                                                   const int* __restrict__ gstart,
                                                   float* __restrict__ out) {
    __shared__ float sW[16 * 32];
    __shared__ float sb[16];
    int tid = threadIdx.x;
    for (int i = tid; i < 16 * 32; i += 256) sW[i] = Wroot[i];
    if (tid < 16) sb[tid] = b[tid];
    __syncthreads();
    int idx = blockIdx.x * 256 + tid;   // (g, o)
    if (idx >= N_GRAPHS * 16) return;
    int g = idx >> 4;
    int o = idx & 15;
    float cnt = (float)(gstart[g + 1] - gstart[g]);
    const float* p = psum + g * 48;
    float acc = p[o] + cnt * sb[o];
#pragma unroll
    for (int k = 0; k < 32; ++k) acc += p[16 + k] * sW[o * 32 + k];
    out[idx] = fast_tanh(acc / fmaxf(cnt, 1.f));
}

extern "C" void kernel_launch(void* const* d_in, const int* in_sizes, int n_in,
                              void* d_out, int out_size, void* d_ws, size_t ws_size,
                              hipStream_t stream) {
    const float* x      = (const float*)d_in[0];
    const int*   eidx   = (const int*)d_in[1];
    const int*   src    = eidx;
    const int*   dst    = eidx + N_EDGES;
    const int*   batch  = (const int*)d_in[2];
    const float* Wrel0  = (const float*)d_in[3];
    const float* b0     = (const float*)d_in[4];
    const float* Wroot0 = (const float*)d_in[5];
    const float* Wrel1  = (const float*)d_in[6];
    const float* b1     = (const float*)d_in[7];
    const float* Wroot1 = (const float*)d_in[8];
    const float* Wrel2  = (const float*)d_in[9];
    const float* b2     = (const float*)d_in[10];
    const float* Wroot2 = (const float*)d_in[11];
    float* out = (float*)d_out;

    // ---- workspace layout ----
    float* ws   = (float*)d_ws;
    float* agg  = ws;                                  // N*38 f32 (reused 38/32/16)
    float* h1   = agg + (size_t)N_NODES * 38;          // N*64 f32
    float* y    = h1  + (size_t)N_NODES * 64;          // bf16 y buffers live here
    float* h2   = y   + (size_t)N_NODES * 32;          // N*32 f32 (aliased as ebuf during CSR build)
    float* psum = h2  + (size_t)N_NODES * 32;          // 256*48
    int* rowptr      = (int*)(psum + N_GRAPHS * 48);   // N
    int* rowend      = rowptr + N_NODES;               // N
    int* gstart      = rowend + N_NODES;               // 257 (pad 260)
    int* bucket_cnt  = gstart + 260;                   // NB (pad 400)
    int* bucket_base = bucket_cnt + 400;               // NB+1 (pad 400)
    int* blockoff    = bucket_base + 400;              // NBLK*NB
    int* elist       = blockoff + NBLK * NB;           // E
    int* ebuf        = (int*)h2;                       // E (alias; dead before h2 is written)
    unsigned int* xb = (unsigned int*)h1;              // N*19 pairs (alias; dead before h1 is written)
    unsigned int* yb = (unsigned int*)y;               // N*16 / N*8 pairs

    // ---- cast x to bf16 pairs (aliases h1; dead after layer-0 gather) ----
    k_cast_bf16<<<(N_NODES * 19 + 255) / 256, 256, 0, stream>>>(x, xb, N_NODES * 19);

    // ---- CSR build + graph boundaries ----
    hipMemsetAsync(bucket_cnt, 0, sizeof(int) * NB, stream);
    k_hist<<<NBLK, 256, 0, stream>>>(dst, bucket_cnt, blockoff);
    k_scan_buckets<<<1, 512, 0, stream>>>(bucket_cnt, bucket_base);
    k_scatter_buckets<<<NBLK, 256, 0, stream>>>(src, dst, bucket_base, blockoff, ebuf);
    k_bucket_csr<<<NB, 256, 0, stream>>>(ebuf, bucket_base, rowptr, rowend, elist);
    k_graph_start<<<(N_NODES + 255) / 256, 256, 0, stream>>>(batch, gstart);

    // ---- Layer 0: gather bf16 x (19 pairs), then fused double-linear ----
    k_gather_bf16<19><<<(N_NODES * 19 + 255) / 256, 256, 0, stream>>>(xb, rowptr, rowend, elist, agg);
    k_update0<<<(N_NODES * 64 + 255) / 256, 256, 0, stream>>>(agg, x, Wrel0, b0, Wroot0, h1);

    // ---- Layer 1: transform first (64->32, bf16 out), gather 16 pairs ----
    k_linear_bf16<64, 32><<<(N_NODES * 32 + 255) / 256, 256, 0, stream>>>(h1, Wrel1, (unsigned short*)yb);
    k_gather_bf16<16><<<(N_NODES * 16 + 255) / 256, 256, 0, stream>>>(yb, rowptr, rowend, elist, agg);
    k_update_mid<64, 32><<<(N_NODES * 32 + 255) / 256, 256, 0, stream>>>(agg, h1, Wroot1, b1, h2);

    // ---- Layer 2: transform first (32->16, bf16 out), gather 8 pairs ----
    k_linear_bf16<32, 16><<<(N_NODES * 16 + 255) / 256, 256, 0, stream>>>(h2, Wrel2, (unsigned short*)yb);
    k_gather_bf16<8><<<(N_NODES * 8 + 255) / 256, 256, 0, stream>>>(yb, rowptr, rowend, elist, agg);

    // ---- pool: per-graph sums (no atomics), then tiny finalize ----
    k_pool<<<N_GRAPHS, 256, 0, stream>>>(agg, h2, gstart, psum);
    k_finalize2<<<(N_GRAPHS * 16 + 255) / 256, 256, 0, stream>>>(psum, Wroot2, b2, gstart, out);
}

// Round 6
// 364.194 us; speedup vs baseline: 4.1207x; 1.4848x over previous
//
#include <hip/hip_runtime.h>
#include <math.h>

#define N_NODES  100000
#define N_EDGES  3200000
#define N_GRAPHS 256

// DIMS = [38, 64, 32, 16]

#define BSHIFT 8
#define NB ((N_NODES + 255) >> 8)                 // 391 buckets of 256 nodes
#define NBLK 640
#define EPB ((N_EDGES + NBLK - 1) / NBLK)         // 5000 edges per block

__device__ __forceinline__ float fast_tanh(float x) {
    x = fminf(20.f, fmaxf(-20.f, x));
    float e = __expf(2.f * x);
    return (e - 1.f) / (e + 1.f);
}

// pack two f32 -> bf16x2 (RNE)
__device__ __forceinline__ unsigned int pack_bf2(float a, float b) {
    unsigned int ua = __float_as_uint(a);
    unsigned int ub = __float_as_uint(b);
    ua += 0x7fffu + ((ua >> 16) & 1u);
    ub += 0x7fffu + ((ub >> 16) & 1u);
    return (ua >> 16) | (ub & 0xffff0000u);
}

// ---------------- CSR build: two-level counting sort, LDS atomics only ----------------

__global__ __launch_bounds__(256) void k_hist(const int* __restrict__ dst,
                                              int* __restrict__ bucket_cnt,
                                              int* __restrict__ blockoff) {
    __shared__ int hist[NB];
    int tid = threadIdx.x;
    int b = blockIdx.x;
    for (int i = tid; i < NB; i += 256) hist[i] = 0;
    __syncthreads();
    int lo = b * EPB;
    int hi = min(lo + EPB, N_EDGES);
    for (int e = lo + tid; e < hi; e += 256)
        atomicAdd(&hist[dst[e] >> BSHIFT], 1);
    __syncthreads();
    for (int i = tid; i < NB; i += 256) {
        int c = hist[i];
        blockoff[b * NB + i] = (c > 0) ? atomicAdd(&bucket_cnt[i], c) : 0;
    }
}

__global__ __launch_bounds__(512) void k_scan_buckets(const int* __restrict__ bucket_cnt,
                                                      int* __restrict__ bucket_base) {
    __shared__ int sd[512];
    int tid = threadIdx.x;
    int v = (tid < NB) ? bucket_cnt[tid] : 0;
    int val = v;
    sd[tid] = val;
    __syncthreads();
#pragma unroll
    for (int off = 1; off < 512; off <<= 1) {
        int t = (tid >= off) ? sd[tid - off] : 0;
        __syncthreads();
        val += t;
        sd[tid] = val;
        __syncthreads();
    }
    if (tid < NB) {
        bucket_base[tid] = val - v;
        if (tid == NB - 1) bucket_base[NB] = val;
    }
}

__global__ __launch_bounds__(256) void k_scatter_buckets(const int* __restrict__ src,
                                                         const int* __restrict__ dst,
                                                         const int* __restrict__ bucket_base,
                                                         const int* __restrict__ blockoff,
                                                         int* __restrict__ ebuf) {
    __shared__ int base[NB];
    __shared__ int cur[NB];
    int tid = threadIdx.x;
    int b = blockIdx.x;
    for (int i = tid; i < NB; i += 256) {
        base[i] = bucket_base[i] + blockoff[b * NB + i];
        cur[i] = 0;
    }
    __syncthreads();
    int lo = b * EPB;
    int hi = min(lo + EPB, N_EDGES);
    for (int e = lo + tid; e < hi; e += 256) {
        int d = dst[e];
        int bin = d >> BSHIFT;
        int r = atomicAdd(&cur[bin], 1);
        ebuf[base[bin] + r] = src[e] | ((d & 255) << 17);
    }
}

__global__ __launch_bounds__(256) void k_bucket_csr(const int* __restrict__ ebuf,
                                                    const int* __restrict__ bucket_base,
                                                    int* __restrict__ rowptr,
                                                    int* __restrict__ rowend,
                                                    int* __restrict__ elist) {
    __shared__ int cnt[256];
    __shared__ int nb[256];
    __shared__ int cur[256];
    __shared__ int sscan[256];
    int b = blockIdx.x;
    int tid = threadIdx.x;
    int e0 = bucket_base[b];
    int e1 = bucket_base[b + 1];
    cnt[tid] = 0;
    cur[tid] = 0;
    __syncthreads();
    for (int j = e0 + tid; j < e1; j += 256)
        atomicAdd(&cnt[ebuf[j] >> 17], 1);
    __syncthreads();
    int v = cnt[tid];
    int val = v;
    sscan[tid] = val;
    __syncthreads();
#pragma unroll
    for (int off = 1; off < 256; off <<= 1) {
        int t = (tid >= off) ? sscan[tid - off] : 0;
        __syncthreads();
        val += t;
        sscan[tid] = val;
        __syncthreads();
    }
    int excl = val - v;
    nb[tid] = excl;
    int node = (b << BSHIFT) + tid;
    if (node < N_NODES) {
        rowptr[node] = e0 + excl;
        rowend[node] = e0 + val;
    }
    __syncthreads();
    for (int j = e0 + tid; j < e1; j += 256) {
        int w = ebuf[j];
        int dl = w >> 17;
        int r = atomicAdd(&cur[dl], 1);
        elist[e0 + nb[dl] + r] = w & 0x1FFFF;
    }
}

// ---------------- cast f32 -> packed bf16 pairs ----------------
__global__ __launch_bounds__(256) void k_cast_bf16(const float* __restrict__ in,
                                                   unsigned int* __restrict__ out,
                                                   int n_pairs) {
    int i = blockIdx.x * 256 + threadIdx.x;
    if (i >= n_pairs) return;
    float2 v = ((const float2*)in)[i];
    out[i] = pack_bf2(v.x, v.y);
}

// ---------------- gather (bf16 pairs) ----------------
template<int DIM2>
__global__ __launch_bounds__(256) void k_gather_bf16(const unsigned int* __restrict__ feat,
                                                     const int* __restrict__ rowptr,
                                                     const int* __restrict__ rowend,
                                                     const int* __restrict__ elist,
                                                     float* __restrict__ agg) {
    int idx = blockIdx.x * 256 + threadIdx.x;
    if (idx >= N_NODES * DIM2) return;
    int n = idx / DIM2;
    int p = idx - n * DIM2;
    int j = rowptr[n];
    int e = rowend[n];
    float a0 = 0.f, a1 = 0.f;
    for (; j + 3 < e; j += 4) {
        int s0 = elist[j];
        int s1 = elist[j + 1];
        int s2 = elist[j + 2];
        int s3 = elist[j + 3];
        unsigned int w0 = feat[s0 * DIM2 + p];
        unsigned int w1 = feat[s1 * DIM2 + p];
        unsigned int w2 = feat[s2 * DIM2 + p];
        unsigned int w3 = feat[s3 * DIM2 + p];
        a0 += __uint_as_float(w0 << 16);
        a1 += __uint_as_float(w0 & 0xffff0000u);
        a0 += __uint_as_float(w1 << 16);
        a1 += __uint_as_float(w1 & 0xffff0000u);
        a0 += __uint_as_float(w2 << 16);
        a1 += __uint_as_float(w2 & 0xffff0000u);
        a0 += __uint_as_float(w3 << 16);
        a1 += __uint_as_float(w3 & 0xffff0000u);
    }
    for (; j < e; ++j) {
        unsigned int w = feat[elist[j] * DIM2 + p];
        a0 += __uint_as_float(w << 16);
        a1 += __uint_as_float(w & 0xffff0000u);
    }
    agg[n * (2 * DIM2) + 2 * p]     = a0;
    agg[n * (2 * DIM2) + 2 * p + 1] = a1;
}

// -------- fused layer0+layer1-dense:
// per node: h1 = tanh(agg0@Wrel0^T + b0 + x@Wroot0^T)   (registers only)
//           y1b = bf16(h1@Wrel1^T), r1 = h1@Wroot1^T + b1
__global__ __launch_bounds__(256) void k_fused0(const float* __restrict__ agg,
                                                const float* __restrict__ x,
                                                const float* __restrict__ Wrel0,
                                                const float* __restrict__ b0,
                                                const float* __restrict__ Wroot0,
                                                const float* __restrict__ Wrel1,
                                                const float* __restrict__ b1,
                                                const float* __restrict__ Wroot1,
                                                unsigned int* __restrict__ y1b,   // [N][16] bf16 pairs
                                                float* __restrict__ r1) {         // [N][32]
    __shared__ float sWr[64 * 40];    // Wrel0 padded to stride 40
    __shared__ float sWt[64 * 40];    // Wroot0 padded
    __shared__ float sW1r[64 * 32];   // Wrel1 transposed: [k][j]
    __shared__ float sW1t[64 * 32];   // Wroot1 transposed
    __shared__ float sb0[64];
    __shared__ float sb1[32];
    int tid = threadIdx.x;
    for (int i = tid; i < 64 * 40; i += 256) {
        int o = i / 40, d = i - o * 40;
        sWr[i] = (d < 38) ? Wrel0[o * 38 + d] : 0.f;
        sWt[i] = (d < 38) ? Wroot0[o * 38 + d] : 0.f;
    }
    for (int i = tid; i < 64 * 32; i += 256) {
        int k = i >> 5, j = i & 31;
        sW1r[i] = Wrel1[j * 64 + k];
        sW1t[i] = Wroot1[j * 64 + k];
    }
    if (tid < 64) sb0[tid] = b0[tid];
    if (tid < 32) sb1[tid] = b1[tid];
    __syncthreads();

    int n = blockIdx.x * 256 + tid;
    if (n >= N_NODES) return;

    float xa[40], xx[40];
    const float2* a2 = (const float2*)(agg + (size_t)n * 38);
    const float2* x2 = (const float2*)(x + (size_t)n * 38);
#pragma unroll
    for (int i = 0; i < 19; ++i) {
        float2 va = a2[i]; xa[2 * i] = va.x; xa[2 * i + 1] = va.y;
        float2 vx = x2[i]; xx[2 * i] = vx.x; xx[2 * i + 1] = vx.y;
    }
    xa[38] = xa[39] = 0.f;
    xx[38] = xx[39] = 0.f;

    float y1[32], rr[32];
#pragma unroll
    for (int j = 0; j < 32; ++j) { y1[j] = 0.f; rr[j] = sb1[j]; }

#pragma unroll 4
    for (int o = 0; o < 64; ++o) {
        float acc = sb0[o];
        const float4* wr = (const float4*)(sWr + o * 40);  // uniform addr -> broadcast
        const float4* wt = (const float4*)(sWt + o * 40);
#pragma unroll
        for (int d = 0; d < 10; ++d) {
            float4 a = wr[d], b = wt[d];
            acc += xa[4 * d] * a.x + xa[4 * d + 1] * a.y + xa[4 * d + 2] * a.z + xa[4 * d + 3] * a.w;
            acc += xx[4 * d] * b.x + xx[4 * d + 1] * b.y + xx[4 * d + 2] * b.z + xx[4 * d + 3] * b.w;
        }
        float h = fast_tanh(acc);
        const float4* w1 = (const float4*)(sW1r + o * 32);
        const float4* w2 = (const float4*)(sW1t + o * 32);
#pragma unroll
        for (int j = 0; j < 8; ++j) {
            float4 a = w1[j], b = w2[j];
            y1[4 * j]     += h * a.x; y1[4 * j + 1] += h * a.y;
            y1[4 * j + 2] += h * a.z; y1[4 * j + 3] += h * a.w;
            rr[4 * j]     += h * b.x; rr[4 * j + 1] += h * b.y;
            rr[4 * j + 2] += h * b.z; rr[4 * j + 3] += h * b.w;
        }
    }

    unsigned int* yo = y1b + (size_t)n * 16;
#pragma unroll
    for (int p = 0; p < 16; ++p) yo[p] = pack_bf2(y1[2 * p], y1[2 * p + 1]);
    float4* ro = (float4*)(r1 + (size_t)n * 32);
#pragma unroll
    for (int j = 0; j < 8; ++j) ro[j] = make_float4(rr[4 * j], rr[4 * j + 1], rr[4 * j + 2], rr[4 * j + 3]);
}

// -------- fused layer1-finish + layer2-rel:
// h2 = tanh(agg1 + r1); y2b = bf16(h2@Wrel2^T); store h2 for pooling
__global__ __launch_bounds__(256) void k_fused1(const float* __restrict__ agg,   // [N][32]
                                                const float* __restrict__ r1,    // [N][32]
                                                const float* __restrict__ Wrel2, // [16][32]
                                                float* __restrict__ h2,          // [N][32]
                                                unsigned int* __restrict__ y2b)  // [N][8]
{
    __shared__ float sW[32 * 16];   // transposed [k][j]
    int tid = threadIdx.x;
    for (int i = tid; i < 512; i += 256) {
        int k = i >> 4, j = i & 15;
        sW[i] = Wrel2[j * 32 + k];
    }
    __syncthreads();
    int n = blockIdx.x * 256 + tid;
    if (n >= N_NODES) return;
    const float4* a4 = (const float4*)(agg + (size_t)n * 32);
    const float4* r4 = (const float4*)(r1 + (size_t)n * 32);
    float h[32];
#pragma unroll
    for (int i = 0; i < 8; ++i) {
        float4 a = a4[i], r = r4[i];
        h[4 * i]     = fast_tanh(a.x + r.x);
        h[4 * i + 1] = fast_tanh(a.y + r.y);
        h[4 * i + 2] = fast_tanh(a.z + r.z);
        h[4 * i + 3] = fast_tanh(a.w + r.w);
    }
    float4* ho = (float4*)(h2 + (size_t)n * 32);
#pragma unroll
    for (int i = 0; i < 8; ++i) ho[i] = make_float4(h[4 * i], h[4 * i + 1], h[4 * i + 2], h[4 * i + 3]);
    float y[16];
#pragma unroll
    for (int j = 0; j < 16; ++j) y[j] = 0.f;
#pragma unroll
    for (int k = 0; k < 32; ++k) {
        const float4* w = (const float4*)(sW + k * 16);
#pragma unroll
        for (int j = 0; j < 4; ++j) {
            float4 wv = w[j];
            y[4 * j]     += h[k] * wv.x; y[4 * j + 1] += h[k] * wv.y;
            y[4 * j + 2] += h[k] * wv.z; y[4 * j + 3] += h[k] * wv.w;
        }
    }
    unsigned int* yo = y2b + (size_t)n * 8;
#pragma unroll
    for (int p = 0; p < 8; ++p) yo[p] = pack_bf2(y[2 * p], y[2 * p + 1]);
}

// -------- graph boundaries from sorted batch vector --------
__global__ __launch_bounds__(256) void k_graph_start(const int* __restrict__ batch,
                                                     int* __restrict__ gstart) {
    int i = blockIdx.x * 256 + threadIdx.x;
    if (i >= N_NODES) return;
    int g = batch[i];
    int gp = (i == 0) ? -1 : batch[i - 1];
    for (int gg = gp + 1; gg <= g; ++gg) gstart[gg] = i;
    if (i == N_NODES - 1)
        for (int gg = g + 1; gg <= N_GRAPHS; ++gg) gstart[gg] = N_NODES;
}

// -------- per-graph sums of agg[16] and h2[32], no atomics (batch sorted) --------
__global__ __launch_bounds__(256) void k_pool(const float* __restrict__ agg,   // [N][16]
                                              const float* __restrict__ h2,    // [N][32]
                                              const int* __restrict__ gstart,
                                              float* __restrict__ psum)        // [G][48]
{
    __shared__ float part[4][48];
    int g = blockIdx.x;
    int wave = threadIdx.x >> 6;
    int lane = threadIdx.x & 63;
    int s = gstart[g], e = gstart[g + 1];
    if (lane < 48) {
        float a0 = 0.f, a1 = 0.f;
        if (lane < 16) {
            int n = s + wave;
            for (; n + 4 < e; n += 8) {
                a0 += agg[n * 16 + lane];
                a1 += agg[(n + 4) * 16 + lane];
            }
            if (n < e) a0 += agg[n * 16 + lane];
        } else {
            int d = lane - 16;
            int n = s + wave;
            for (; n + 4 < e; n += 8) {
                a0 += h2[n * 32 + d];
                a1 += h2[(n + 4) * 32 + d];
            }
            if (n < e) a0 += h2[n * 32 + d];
        }
        part[wave][lane] = a0 + a1;
    }
    __syncthreads();
    if (threadIdx.x < 48)
        psum[g * 48 + threadIdx.x] = part[0][threadIdx.x] + part[1][threadIdx.x]
                                   + part[2][threadIdx.x] + part[3][threadIdx.x];
}

// -------- finalize: out[g][o] = tanh((psum16[o] + cnt*b[o] + psum32 . W[o]) / cnt) --------
__global__ __launch_bounds__(256) void k_finalize2(const float* __restrict__ psum,  // [G][48]
                                                   const float* __restrict__ Wroot, // [16][32]
                                                   const float* __restrict__ b,
                                                   const int* __restrict__ gstart,
                                                   float* __restrict__ out) {
    __shared__ float sW[16 * 32];
    __shared__ float sb[16];
    int tid = threadIdx.x;
    for (int i = tid; i < 16 * 32; i += 256) sW[i] = Wroot[i];
    if (tid < 16) sb[tid] = b[tid];
    __syncthreads();
    int idx = blockIdx.x * 256 + tid;   // (g, o)
    if (idx >= N_GRAPHS * 16) return;
    int g = idx >> 4;
    int o = idx & 15;
    float cnt = (float)(gstart[g + 1] - gstart[g]);
    const float* p = psum + g * 48;
    float acc = p[o] + cnt * sb[o];
#pragma unroll
    for (int k = 0; k < 32; ++k) acc += p[16 + k] * sW[o * 32 + k];
    out[idx] = fast_tanh(acc / fmaxf(cnt, 1.f));
}

extern "C" void kernel_launch(void* const* d_in, const int* in_sizes, int n_in,
                              void* d_out, int out_size, void* d_ws, size_t ws_size,
                              hipStream_t stream) {
    const float* x      = (const float*)d_in[0];
    const int*   eidx   = (const int*)d_in[1];
    const int*   src    = eidx;
    const int*   dst    = eidx + N_EDGES;
    const int*   batch  = (const int*)d_in[2];
    const float* Wrel0  = (const float*)d_in[3];
    const float* b0     = (const float*)d_in[4];
    const float* Wroot0 = (const float*)d_in[5];
    const float* Wrel1  = (const float*)d_in[6];
    const float* b1     = (const float*)d_in[7];
    const float* Wroot1 = (const float*)d_in[8];
    const float* Wrel2  = (const float*)d_in[9];
    const float* b2     = (const float*)d_in[10];
    const float* Wroot2 = (const float*)d_in[11];
    float* out = (float*)d_out;

    // ---- workspace layout ----
    float* ws   = (float*)d_ws;
    float* agg  = ws;                                  // N*38 f32 (reused 38/32/16)
    float* r1   = agg + (size_t)N_NODES * 38;          // N*32 f32 (alias: xb before fused0)
    float* h2   = r1  + (size_t)N_NODES * 32;          // N*32 f32 (alias: ebuf during CSR build)
    unsigned int* ybuf = (unsigned int*)(h2 + (size_t)N_NODES * 32); // N*16 uints (y1b; y2b reuses)
    float* psum = (float*)(ybuf + (size_t)N_NODES * 16);             // 256*48
    int* rowptr      = (int*)(psum + N_GRAPHS * 48);   // N
    int* rowend      = rowptr + N_NODES;               // N
    int* gstart      = rowend + N_NODES;               // 257 (pad 260)
    int* bucket_cnt  = gstart + 260;                   // NB (pad 400)
    int* bucket_base = bucket_cnt + 400;               // NB+1 (pad 400)
    int* blockoff    = bucket_base + 400;              // NBLK*NB
    int* elist       = blockoff + NBLK * NB;           // E
    int* ebuf        = (int*)h2;                       // E (alias; dead before h2 is written)
    unsigned int* xb = (unsigned int*)r1;              // N*19 pairs (alias; dead before r1 is written)

    // ---- cast x to bf16 pairs (aliases r1; consumed by gather0 before fused0 writes r1) ----
    k_cast_bf16<<<(N_NODES * 19 + 255) / 256, 256, 0, stream>>>(x, xb, N_NODES * 19);

    // ---- CSR build + graph boundaries ----
    hipMemsetAsync(bucket_cnt, 0, sizeof(int) * NB, stream);
    k_hist<<<NBLK, 256, 0, stream>>>(dst, bucket_cnt, blockoff);
    k_scan_buckets<<<1, 512, 0, stream>>>(bucket_cnt, bucket_base);
    k_scatter_buckets<<<NBLK, 256, 0, stream>>>(src, dst, bucket_base, blockoff, ebuf);
    k_bucket_csr<<<NB, 256, 0, stream>>>(ebuf, bucket_base, rowptr, rowend, elist);
    k_graph_start<<<(N_NODES + 255) / 256, 256, 0, stream>>>(batch, gstart);

    // ---- Layer 0: gather bf16 x (19 pairs), then fused dense (h1 in regs -> y1b, r1) ----
    k_gather_bf16<19><<<(N_NODES * 19 + 255) / 256, 256, 0, stream>>>(xb, rowptr, rowend, elist, agg);
    k_fused0<<<(N_NODES + 255) / 256, 256, 0, stream>>>(agg, x, Wrel0, b0, Wroot0,
                                                        Wrel1, b1, Wroot1, ybuf, r1);

    // ---- Layer 1: gather 16 pairs, then fused finish + layer2-rel ----
    k_gather_bf16<16><<<(N_NODES * 16 + 255) / 256, 256, 0, stream>>>(ybuf, rowptr, rowend, elist, agg);
    k_fused1<<<(N_NODES + 255) / 256, 256, 0, stream>>>(agg, r1, Wrel2, h2, ybuf);

    // ---- Layer 2: gather 8 pairs ----
    k_gather_bf16<8><<<(N_NODES * 8 + 255) / 256, 256, 0, stream>>>(ybuf, rowptr, rowend, elist, agg);

    // ---- pool: per-graph sums (no atomics), then tiny finalize ----
    k_pool<<<N_GRAPHS, 256, 0, stream>>>(agg, h2, gstart, psum);
    k_finalize2<<<(N_GRAPHS * 16 + 255) / 256, 256, 0, stream>>>(psum, Wroot2, b2, gstart, out);
}

// Round 7
// 353.098 us; speedup vs baseline: 4.2501x; 1.0314x over previous
//
#include <hip/hip_runtime.h>
#include <math.h>

#define N_NODES  100000
#define N_EDGES  3200000
#define N_GRAPHS 256

// DIMS = [38, 64, 32, 16]

#define BSHIFT 8
#define NB ((N_NODES + 255) >> 8)                 // 391 buckets of 256 nodes
#define NBLK 1280
#define EPB ((N_EDGES + NBLK - 1) / NBLK)         // 2500 edges per block

typedef _Float16 f16;
typedef _Float16 f16x2 __attribute__((ext_vector_type(2)));

__device__ __forceinline__ float fast_tanh(float x) {
    x = fminf(20.f, fmaxf(-20.f, x));
    float e = __expf(2.f * x);
    return (e - 1.f) / (e + 1.f);
}

// pack two f32 -> bf16x2 (RNE)
__device__ __forceinline__ unsigned int pack_bf2(float a, float b) {
    unsigned int ua = __float_as_uint(a);
    unsigned int ub = __float_as_uint(b);
    ua += 0x7fffu + ((ua >> 16) & 1u);
    ub += 0x7fffu + ((ub >> 16) & 1u);
    return (ua >> 16) | (ub & 0xffff0000u);
}

__device__ __forceinline__ f16x2 u2h(unsigned int u) { union { unsigned int u; f16x2 h; } c; c.u = u; return c.h; }
__device__ __forceinline__ unsigned int h2u(f16x2 h) { union { unsigned int u; f16x2 h; } c; c.h = h; return c.u; }
__device__ __forceinline__ unsigned int mkh2(float a, float b) {
    f16x2 v; v.x = (f16)a; v.y = (f16)b; return h2u(v);
}

__device__ __forceinline__ float fdot2f(f16x2 a, f16x2 b, float c) {
#if __has_builtin(__builtin_amdgcn_fdot2)
    return __builtin_amdgcn_fdot2(a, b, c, false);
#else
    return c + (float)a.x * (float)b.x + (float)a.y * (float)b.y;
#endif
}

// ---------------- CSR build: two-level counting sort, LDS atomics only ----------------

__global__ __launch_bounds__(256) void k_hist(const int* __restrict__ dst,
                                              int* __restrict__ bucket_cnt,
                                              int* __restrict__ blockoff) {
    __shared__ int hist[NB];
    int tid = threadIdx.x;
    int b = blockIdx.x;
    for (int i = tid; i < NB; i += 256) hist[i] = 0;
    __syncthreads();
    int lo = b * EPB;
    int hi = min(lo + EPB, N_EDGES);
    for (int e = lo + tid; e < hi; e += 256)
        atomicAdd(&hist[dst[e] >> BSHIFT], 1);
    __syncthreads();
    for (int i = tid; i < NB; i += 256) {
        int c = hist[i];
        blockoff[b * NB + i] = (c > 0) ? atomicAdd(&bucket_cnt[i], c) : 0;
    }
}

__global__ __launch_bounds__(512) void k_scan_buckets(const int* __restrict__ bucket_cnt,
                                                      int* __restrict__ bucket_base) {
    __shared__ int sd[512];
    int tid = threadIdx.x;
    int v = (tid < NB) ? bucket_cnt[tid] : 0;
    int val = v;
    sd[tid] = val;
    __syncthreads();
#pragma unroll
    for (int off = 1; off < 512; off <<= 1) {
        int t = (tid >= off) ? sd[tid - off] : 0;
        __syncthreads();
        val += t;
        sd[tid] = val;
        __syncthreads();
    }
    if (tid < NB) {
        bucket_base[tid] = val - v;
        if (tid == NB - 1) bucket_base[NB] = val;
    }
}

__global__ __launch_bounds__(256) void k_scatter_buckets(const int* __restrict__ src,
                                                         const int* __restrict__ dst,
                                                         const int* __restrict__ bucket_base,
                                                         const int* __restrict__ blockoff,
                                                         int* __restrict__ ebuf) {
    __shared__ int base[NB];
    __shared__ int cur[NB];
    int tid = threadIdx.x;
    int b = blockIdx.x;
    for (int i = tid; i < NB; i += 256) {
        base[i] = bucket_base[i] + blockoff[b * NB + i];
        cur[i] = 0;
    }
    __syncthreads();
    int lo = b * EPB;
    int hi = min(lo + EPB, N_EDGES);
    for (int e = lo + tid; e < hi; e += 256) {
        int d = dst[e];
        int bin = d >> BSHIFT;
        int r = atomicAdd(&cur[bin], 1);
        ebuf[base[bin] + r] = src[e] | ((d & 255) << 17);
    }
}

__global__ __launch_bounds__(256) void k_bucket_csr(const int* __restrict__ ebuf,
                                                    const int* __restrict__ bucket_base,
                                                    int* __restrict__ rowptr,
                                                    int* __restrict__ rowend,
                                                    int* __restrict__ elist) {
    __shared__ int cnt[256];
    __shared__ int nb[256];
    __shared__ int cur[256];
    __shared__ int sscan[256];
    int b = blockIdx.x;
    int tid = threadIdx.x;
    int e0 = bucket_base[b];
    int e1 = bucket_base[b + 1];
    cnt[tid] = 0;
    cur[tid] = 0;
    __syncthreads();
    for (int j = e0 + tid; j < e1; j += 256)
        atomicAdd(&cnt[ebuf[j] >> 17], 1);
    __syncthreads();
    int v = cnt[tid];
    int val = v;
    sscan[tid] = val;
    __syncthreads();
#pragma unroll
    for (int off = 1; off < 256; off <<= 1) {
        int t = (tid >= off) ? sscan[tid - off] : 0;
        __syncthreads();
        val += t;
        sscan[tid] = val;
        __syncthreads();
    }
    int excl = val - v;
    nb[tid] = excl;
    int node = (b << BSHIFT) + tid;
    if (node < N_NODES) {
        rowptr[node] = e0 + excl;
        rowend[node] = e0 + val;
    }
    __syncthreads();
    for (int j = e0 + tid; j < e1; j += 256) {
        int w = ebuf[j];
        int dl = w >> 17;
        int r = atomicAdd(&cur[dl], 1);
        elist[e0 + nb[dl] + r] = w & 0x1FFFF;
    }
}

// ---------------- cast f32 -> packed bf16 pairs ----------------
__global__ __launch_bounds__(256) void k_cast_bf16(const float* __restrict__ in,
                                                   unsigned int* __restrict__ out,
                                                   int n_pairs) {
    int i = blockIdx.x * 256 + threadIdx.x;
    if (i >= n_pairs) return;
    float2 v = ((const float2*)in)[i];
    out[i] = pack_bf2(v.x, v.y);
}

// ---------------- gather (bf16 pairs) ----------------
template<int DIM2>
__global__ __launch_bounds__(256) void k_gather_bf16(const unsigned int* __restrict__ feat,
                                                     const int* __restrict__ rowptr,
                                                     const int* __restrict__ rowend,
                                                     const int* __restrict__ elist,
                                                     float* __restrict__ agg) {
    int idx = blockIdx.x * 256 + threadIdx.x;
    if (idx >= N_NODES * DIM2) return;
    int n = idx / DIM2;
    int p = idx - n * DIM2;
    int j = rowptr[n];
    int e = rowend[n];
    float a0 = 0.f, a1 = 0.f;
    for (; j + 3 < e; j += 4) {
        int s0 = elist[j];
        int s1 = elist[j + 1];
        int s2 = elist[j + 2];
        int s3 = elist[j + 3];
        unsigned int w0 = feat[s0 * DIM2 + p];
        unsigned int w1 = feat[s1 * DIM2 + p];
        unsigned int w2 = feat[s2 * DIM2 + p];
        unsigned int w3 = feat[s3 * DIM2 + p];
        a0 += __uint_as_float(w0 << 16);
        a1 += __uint_as_float(w0 & 0xffff0000u);
        a0 += __uint_as_float(w1 << 16);
        a1 += __uint_as_float(w1 & 0xffff0000u);
        a0 += __uint_as_float(w2 << 16);
        a1 += __uint_as_float(w2 & 0xffff0000u);
        a0 += __uint_as_float(w3 << 16);
        a1 += __uint_as_float(w3 & 0xffff0000u);
    }
    for (; j < e; ++j) {
        unsigned int w = feat[elist[j] * DIM2 + p];
        a0 += __uint_as_float(w << 16);
        a1 += __uint_as_float(w & 0xffff0000u);
    }
    agg[n * (2 * DIM2) + 2 * p]     = a0;
    agg[n * (2 * DIM2) + 2 * p + 1] = a1;
}

// -------- fused layer0+layer1-dense (f16 dot2, node-pair sharing, lane-half split) --------
// pair of lanes (l, l+32): lanes split the 64 h1-outputs in phase A and the 32
// (y1,r1)-outputs in phase B; each weight ds_read feeds TWO nodes' dot products.
__global__ __launch_bounds__(256) void k_fused0(const float* __restrict__ agg,   // [N][38]
                                                const float* __restrict__ x,     // [N][38]
                                                const float* __restrict__ Wrel0,
                                                const float* __restrict__ b0,
                                                const float* __restrict__ Wroot0,
                                                const float* __restrict__ Wrel1,
                                                const float* __restrict__ b1,
                                                const float* __restrict__ Wroot1,
                                                unsigned int* __restrict__ y1b,  // [N][16] bf16 pairs
                                                float* __restrict__ r1) {        // [N][32]
    __shared__ unsigned int sWr[64 * 20];   // Wrel0 rows as f16 pairs, K padded 38->40
    __shared__ unsigned int sWt[64 * 20];   // Wroot0
    __shared__ unsigned int sW1r[32 * 32];  // Wrel1 packed pairs along o: [op][j]
    __shared__ unsigned int sW1t[32 * 32];  // Wroot1
    __shared__ float sb0[64];
    __shared__ float sb1[32];
    int tid = threadIdx.x;
    for (int i = tid; i < 64 * 20; i += 256) {
        int o = i / 20, d = i - o * 20;
        float a0 = (2 * d     < 38) ? Wrel0[o * 38 + 2 * d]     : 0.f;
        float a1 = (2 * d + 1 < 38) ? Wrel0[o * 38 + 2 * d + 1] : 0.f;
        float t0 = (2 * d     < 38) ? Wroot0[o * 38 + 2 * d]     : 0.f;
        float t1 = (2 * d + 1 < 38) ? Wroot0[o * 38 + 2 * d + 1] : 0.f;
        sWr[i] = mkh2(a0, a1);
        sWt[i] = mkh2(t0, t1);
    }
    for (int i = tid; i < 32 * 32; i += 256) {
        int op = i >> 5, j = i & 31;
        sW1r[i] = mkh2(Wrel1[j * 64 + 2 * op], Wrel1[j * 64 + 2 * op + 1]);
        sW1t[i] = mkh2(Wroot1[j * 64 + 2 * op], Wroot1[j * 64 + 2 * op + 1]);
    }
    if (tid < 64) sb0[tid] = b0[tid];
    if (tid < 32) sb1[tid] = b1[tid];
    __syncthreads();

    int lane = tid & 63;
    int ph = lane & 31;            // node-pair index within wave
    int sh = lane >> 5;            // split half (o-half / j-half)
    int n0 = blockIdx.x * 256 + (tid >> 6) * 64 + 2 * ph;
    if (n0 >= N_NODES) return;     // both sh-halves of a pair exit together
    int n1 = n0 + 1;               // N even, n0 even -> n1 valid

    // pack both nodes' inputs to f16 pairs in registers (20 dwords each)
    unsigned int xa0[20], xx0[20], xa1[20], xx1[20];
    {
        const float2* A0 = (const float2*)(agg + (size_t)n0 * 38);
        const float2* X0 = (const float2*)(x   + (size_t)n0 * 38);
        const float2* A1 = (const float2*)(agg + (size_t)n1 * 38);
        const float2* X1 = (const float2*)(x   + (size_t)n1 * 38);
#pragma unroll
        for (int i = 0; i < 19; ++i) {
            float2 v;
            v = A0[i]; xa0[i] = mkh2(v.x, v.y);
            v = X0[i]; xx0[i] = mkh2(v.x, v.y);
            v = A1[i]; xa1[i] = mkh2(v.x, v.y);
            v = X1[i]; xx1[i] = mkh2(v.x, v.y);
        }
        xa0[19] = 0; xx0[19] = 0; xa1[19] = 0; xx1[19] = 0;
    }

    // ---- phase A: h1 for my 32 o's, both nodes ----
    unsigned int hp0[16], hp1[16];
    int obase = sh * 32;
#pragma unroll
    for (int i = 0; i < 16; ++i) {
        float h00 = 0.f, h01 = 0.f, h10 = 0.f, h11 = 0.f;
#pragma unroll
        for (int par = 0; par < 2; ++par) {
            int o = obase + 2 * i + par;
            float c0 = sb0[o], c1 = 0.f, c2 = 0.f, c3 = 0.f;
            float d0 = sb0[o], d1 = 0.f, d2 = 0.f, d3 = 0.f;
            const uint4* wr = (const uint4*)(sWr + o * 20);
            const uint4* wt = (const uint4*)(sWt + o * 20);
#pragma unroll
            for (int q = 0; q < 5; ++q) {
                uint4 w = wr[q];
                c0 = fdot2f(u2h(xa0[4 * q + 0]), u2h(w.x), c0);
                c1 = fdot2f(u2h(xa0[4 * q + 1]), u2h(w.y), c1);
                c2 = fdot2f(u2h(xa0[4 * q + 2]), u2h(w.z), c2);
                c3 = fdot2f(u2h(xa0[4 * q + 3]), u2h(w.w), c3);
                d0 = fdot2f(u2h(xa1[4 * q + 0]), u2h(w.x), d0);
                d1 = fdot2f(u2h(xa1[4 * q + 1]), u2h(w.y), d1);
                d2 = fdot2f(u2h(xa1[4 * q + 2]), u2h(w.z), d2);
                d3 = fdot2f(u2h(xa1[4 * q + 3]), u2h(w.w), d3);
                uint4 v = wt[q];
                c0 = fdot2f(u2h(xx0[4 * q + 0]), u2h(v.x), c0);
                c1 = fdot2f(u2h(xx0[4 * q + 1]), u2h(v.y), c1);
                c2 = fdot2f(u2h(xx0[4 * q + 2]), u2h(v.z), c2);
                c3 = fdot2f(u2h(xx0[4 * q + 3]), u2h(v.w), c3);
                d0 = fdot2f(u2h(xx1[4 * q + 0]), u2h(v.x), d0);
                d1 = fdot2f(u2h(xx1[4 * q + 1]), u2h(v.y), d1);
                d2 = fdot2f(u2h(xx1[4 * q + 2]), u2h(v.z), d2);
                d3 = fdot2f(u2h(xx1[4 * q + 3]), u2h(v.w), d3);
            }
            float hA = fast_tanh(c0 + c1 + c2 + c3);
            float hB = fast_tanh(d0 + d1 + d2 + d3);
            if (par == 0) { h00 = hA; h10 = hB; }
            else          { h01 = hA; h11 = hB; }
        }
        hp0[i] = mkh2(h00, h01);
        hp1[i] = mkh2(h10, h11);
    }

    // ---- exchange h-halves within the lane pair ----
    unsigned int H0[32], H1[32];
#pragma unroll
    for (int i = 0; i < 16; ++i) {
        unsigned int g0 = (unsigned int)__shfl_xor((int)hp0[i], 32);
        unsigned int g1 = (unsigned int)__shfl_xor((int)hp1[i], 32);
        if (sh == 0) { H0[i] = hp0[i]; H0[16 + i] = g0; H1[i] = hp1[i]; H1[16 + i] = g1; }
        else         { H0[i] = g0; H0[16 + i] = hp0[i]; H1[i] = g1; H1[16 + i] = hp1[i]; }
    }

    // ---- phase B: my 16 j's, both nodes ----
    int jb = sh * 16;
    float y0[16], r0[16], y1v[16], r1v[16];
#pragma unroll
    for (int j = 0; j < 16; ++j) {
        y0[j] = 0.f; y1v[j] = 0.f;
        float bb = sb1[jb + j];
        r0[j] = bb; r1v[j] = bb;
    }
#pragma unroll
    for (int op = 0; op < 32; ++op) {
        f16x2 h0 = u2h(H0[op]);
        f16x2 h1 = u2h(H1[op]);
        const uint4* w1 = (const uint4*)(sW1r + op * 32 + jb);
        const uint4* w2 = (const uint4*)(sW1t + op * 32 + jb);
#pragma unroll
        for (int q = 0; q < 4; ++q) {
            uint4 a = w1[q], b = w2[q];
            y0[4 * q + 0] = fdot2f(h0, u2h(a.x), y0[4 * q + 0]);
            y0[4 * q + 1] = fdot2f(h0, u2h(a.y), y0[4 * q + 1]);
            y0[4 * q + 2] = fdot2f(h0, u2h(a.z), y0[4 * q + 2]);
            y0[4 * q + 3] = fdot2f(h0, u2h(a.w), y0[4 * q + 3]);
            y1v[4 * q + 0] = fdot2f(h1, u2h(a.x), y1v[4 * q + 0]);
            y1v[4 * q + 1] = fdot2f(h1, u2h(a.y), y1v[4 * q + 1]);
            y1v[4 * q + 2] = fdot2f(h1, u2h(a.z), y1v[4 * q + 2]);
            y1v[4 * q + 3] = fdot2f(h1, u2h(a.w), y1v[4 * q + 3]);
            r0[4 * q + 0] = fdot2f(h0, u2h(b.x), r0[4 * q + 0]);
            r0[4 * q + 1] = fdot2f(h0, u2h(b.y), r0[4 * q + 1]);
            r0[4 * q + 2] = fdot2f(h0, u2h(b.z), r0[4 * q + 2]);
            r0[4 * q + 3] = fdot2f(h0, u2h(b.w), r0[4 * q + 3]);
            r1v[4 * q + 0] = fdot2f(h1, u2h(b.x), r1v[4 * q + 0]);
            r1v[4 * q + 1] = fdot2f(h1, u2h(b.y), r1v[4 * q + 1]);
            r1v[4 * q + 2] = fdot2f(h1, u2h(b.z), r1v[4 * q + 2]);
            r1v[4 * q + 3] = fdot2f(h1, u2h(b.w), r1v[4 * q + 3]);
        }
    }

    // ---- stores: each lane writes its j-range for both nodes ----
    unsigned int* yo0 = y1b + (size_t)n0 * 16 + (jb >> 1);
    unsigned int* yo1 = y1b + (size_t)n1 * 16 + (jb >> 1);
#pragma unroll
    for (int p = 0; p < 8; ++p) {
        yo0[p] = pack_bf2(y0[2 * p], y0[2 * p + 1]);
        yo1[p] = pack_bf2(y1v[2 * p], y1v[2 * p + 1]);
    }
    float4* ro0 = (float4*)(r1 + (size_t)n0 * 32 + jb);
    float4* ro1 = (float4*)(r1 + (size_t)n1 * 32 + jb);
#pragma unroll
    for (int q = 0; q < 4; ++q) {
        ro0[q] = make_float4(r0[4 * q], r0[4 * q + 1], r0[4 * q + 2], r0[4 * q + 3]);
        ro1[q] = make_float4(r1v[4 * q], r1v[4 * q + 1], r1v[4 * q + 2], r1v[4 * q + 3]);
    }
}

// -------- fused layer1-finish + layer2-rel --------
__global__ __launch_bounds__(256) void k_fused1(const float* __restrict__ agg,   // [N][32]
                                                const float* __restrict__ r1,    // [N][32]
                                                const float* __restrict__ Wrel2, // [16][32]
                                                float* __restrict__ h2,          // [N][32]
                                                unsigned int* __restrict__ y2b)  // [N][8]
{
    __shared__ float sW[32 * 16];   // transposed [k][j]
    int tid = threadIdx.x;
    for (int i = tid; i < 512; i += 256) {
        int k = i >> 4, j = i & 15;
        sW[i] = Wrel2[j * 32 + k];
    }
    __syncthreads();
    int n = blockIdx.x * 256 + tid;
    if (n >= N_NODES) return;
    const float4* a4 = (const float4*)(agg + (size_t)n * 32);
    const float4* r4 = (const float4*)(r1 + (size_t)n * 32);
    float h[32];
#pragma unroll
    for (int i = 0; i < 8; ++i) {
        float4 a = a4[i], r = r4[i];
        h[4 * i]     = fast_tanh(a.x + r.x);
        h[4 * i + 1] = fast_tanh(a.y + r.y);
        h[4 * i + 2] = fast_tanh(a.z + r.z);
        h[4 * i + 3] = fast_tanh(a.w + r.w);
    }
    float4* ho = (float4*)(h2 + (size_t)n * 32);
#pragma unroll
    for (int i = 0; i < 8; ++i) ho[i] = make_float4(h[4 * i], h[4 * i + 1], h[4 * i + 2], h[4 * i + 3]);
    float y[16];
#pragma unroll
    for (int j = 0; j < 16; ++j) y[j] = 0.f;
#pragma unroll
    for (int k = 0; k < 32; ++k) {
        const float4* w = (const float4*)(sW + k * 16);
#pragma unroll
        for (int j = 0; j < 4; ++j) {
            float4 wv = w[j];
            y[4 * j]     += h[k] * wv.x; y[4 * j + 1] += h[k] * wv.y;
            y[4 * j + 2] += h[k] * wv.z; y[4 * j + 3] += h[k] * wv.w;
        }
    }
    unsigned int* yo = y2b + (size_t)n * 8;
#pragma unroll
    for (int p = 0; p < 8; ++p) yo[p] = pack_bf2(y[2 * p], y[2 * p + 1]);
}

// -------- graph boundaries from sorted batch vector --------
__global__ __launch_bounds__(256) void k_graph_start(const int* __restrict__ batch,
                                                     int* __restrict__ gstart) {
    int i = blockIdx.x * 256 + threadIdx.x;
    if (i >= N_NODES) return;
    int g = batch[i];
    int gp = (i == 0) ? -1 : batch[i - 1];
    for (int gg = gp + 1; gg <= g; ++gg) gstart[gg] = i;
    if (i == N_NODES - 1)
        for (int gg = g + 1; gg <= N_GRAPHS; ++gg) gstart[gg] = N_NODES;
}

// -------- per-graph sums of agg[16] and h2[32], no atomics (batch sorted) --------
__global__ __launch_bounds__(256) void k_pool(const float* __restrict__ agg,   // [N][16]
                                              const float* __restrict__ h2,    // [N][32]
                                              const int* __restrict__ gstart,
                                              float* __restrict__ psum)        // [G][48]
{
    __shared__ float part[4][48];
    int g = blockIdx.x;
    int wave = threadIdx.x >> 6;
    int lane = threadIdx.x & 63;
    int s = gstart[g], e = gstart[g + 1];
    if (lane < 48) {
        float a0 = 0.f, a1 = 0.f;
        if (lane < 16) {
            int n = s + wave;
            for (; n + 4 < e; n += 8) {
                a0 += agg[n * 16 + lane];
                a1 += agg[(n + 4) * 16 + lane];
            }
            if (n < e) a0 += agg[n * 16 + lane];
        } else {
            int d = lane - 16;
            int n = s + wave;
            for (; n + 4 < e; n += 8) {
                a0 += h2[n * 32 + d];
                a1 += h2[(n + 4) * 32 + d];
            }
            if (n < e) a0 += h2[n * 32 + d];
        }
        part[wave][lane] = a0 + a1;
    }
    __syncthreads();
    if (threadIdx.x < 48)
        psum[g * 48 + threadIdx.x] = part[0][threadIdx.x] + part[1][threadIdx.x]
                                   + part[2][threadIdx.x] + part[3][threadIdx.x];
}

// -------- finalize: out[g][o] = tanh((psum16[o] + cnt*b[o] + psum32 . W[o]) / cnt) --------
__global__ __launch_bounds__(256) void k_finalize2(const float* __restrict__ psum,  // [G][48]
                                                   const float* __restrict__ Wroot, // [16][32]
                                                   const float* __restrict__ b,
                                                   const int* __restrict__ gstart,
                                                   float* __restrict__ out) {
    __shared__ float sW[16 * 32];
    __shared__ float sb[16];
    int tid = threadIdx.x;
    for (int i = tid; i < 16 * 32; i += 256) sW[i] = Wroot[i];
    if (tid < 16) sb[tid] = b[tid];
    __syncthreads();
    int idx = blockIdx.x * 256 + tid;   // (g, o)
    if (idx >= N_GRAPHS * 16) return;
    int g = idx >> 4;
    int o = idx & 15;
    float cnt = (float)(gstart[g + 1] - gstart[g]);
    const float* p = psum + g * 48;
    float acc = p[o] + cnt * sb[o];
#pragma unroll
    for (int k = 0; k < 32; ++k) acc += p[16 + k] * sW[o * 32 + k];
    out[idx] = fast_tanh(acc / fmaxf(cnt, 1.f));
}

extern "C" void kernel_launch(void* const* d_in, const int* in_sizes, int n_in,
                              void* d_out, int out_size, void* d_ws, size_t ws_size,
                              hipStream_t stream) {
    const float* x      = (const float*)d_in[0];
    const int*   eidx   = (const int*)d_in[1];
    const int*   src    = eidx;
    const int*   dst    = eidx + N_EDGES;
    const int*   batch  = (const int*)d_in[2];
    const float* Wrel0  = (const float*)d_in[3];
    const float* b0     = (const float*)d_in[4];
    const float* Wroot0 = (const float*)d_in[5];
    const float* Wrel1  = (const float*)d_in[6];
    const float* b1     = (const float*)d_in[7];
    const float* Wroot1 = (const float*)d_in[8];
    const float* Wrel2  = (const float*)d_in[9];
    const float* b2     = (const float*)d_in[10];
    const float* Wroot2 = (const float*)d_in[11];
    float* out = (float*)d_out;

    // ---- workspace layout ----
    float* ws   = (float*)d_ws;
    float* agg  = ws;                                  // N*38 f32 (reused 38/32/16)
    float* r1   = agg + (size_t)N_NODES * 38;          // N*32 f32 (alias: xb before fused0)
    float* h2   = r1  + (size_t)N_NODES * 32;          // N*32 f32 (alias: ebuf during CSR build)
    unsigned int* ybuf = (unsigned int*)(h2 + (size_t)N_NODES * 32); // N*16 uints (y1b; y2b reuses)
    float* psum = (float*)(ybuf + (size_t)N_NODES * 16);             // 256*48
    int* rowptr      = (int*)(psum + N_GRAPHS * 48);   // N
    int* rowend      = rowptr + N_NODES;               // N
    int* gstart      = rowend + N_NODES;               // 257 (pad 260)
    int* bucket_cnt  = gstart + 260;                   // NB (pad 400)
    int* bucket_base = bucket_cnt + 400;               // NB+1 (pad 400)
    int* blockoff    = bucket_base + 400;              // NBLK*NB
    int* elist       = blockoff + (size_t)NBLK * NB;   // E
    int* ebuf        = (int*)h2;                       // E (alias; dead before h2 is written)
    unsigned int* xb = (unsigned int*)r1;              // N*19 pairs (alias; dead before r1 is written)

    // ---- cast x to bf16 pairs (aliases r1; consumed by gather0 before fused0 writes r1) ----
    k_cast_bf16<<<(N_NODES * 19 + 255) / 256, 256, 0, stream>>>(x, xb, N_NODES * 19);

    // ---- CSR build + graph boundaries ----
    hipMemsetAsync(bucket_cnt, 0, sizeof(int) * NB, stream);
    k_hist<<<NBLK, 256, 0, stream>>>(dst, bucket_cnt, blockoff);
    k_scan_buckets<<<1, 512, 0, stream>>>(bucket_cnt, bucket_base);
    k_scatter_buckets<<<NBLK, 256, 0, stream>>>(src, dst, bucket_base, blockoff, ebuf);
    k_bucket_csr<<<NB, 256, 0, stream>>>(ebuf, bucket_base, rowptr, rowend, elist);
    k_graph_start<<<(N_NODES + 255) / 256, 256, 0, stream>>>(batch, gstart);

    // ---- Layer 0: gather bf16 x (19 pairs), then fused dense (h1 in regs -> ybuf, r1) ----
    k_gather_bf16<19><<<(N_NODES * 19 + 255) / 256, 256, 0, stream>>>(xb, rowptr, rowend, elist, agg);
    k_fused0<<<(N_NODES + 255) / 256, 256, 0, stream>>>(agg, x, Wrel0, b0, Wroot0,
                                                        Wrel1, b1, Wroot1, ybuf, r1);

    // ---- Layer 1: gather 16 pairs, then fused finish + layer2-rel ----
    k_gather_bf16<16><<<(N_NODES * 16 + 255) / 256, 256, 0, stream>>>(ybuf, rowptr, rowend, elist, agg);
    k_fused1<<<(N_NODES + 255) / 256, 256, 0, stream>>>(agg, r1, Wrel2, h2, ybuf);

    // ---- Layer 2: gather 8 pairs ----
    k_gather_bf16<8><<<(N_NODES * 8 + 255) / 256, 256, 0, stream>>>(ybuf, rowptr, rowend, elist, agg);

    // ---- pool: per-graph sums (no atomics), then tiny finalize ----
    k_pool<<<N_GRAPHS, 256, 0, stream>>>(agg, h2, gstart, psum);
    k_finalize2<<<(N_GRAPHS * 16 + 255) / 256, 256, 0, stream>>>(psum, Wroot2, b2, gstart, out);
}

// Round 8
// 352.929 us; speedup vs baseline: 4.2522x; 1.0005x over previous
//
#include <hip/hip_runtime.h>
#include <math.h>

#define N_NODES  100000
#define N_EDGES  3200000
#define N_GRAPHS 256

// DIMS = [38, 64, 32, 16]

#define BSHIFT 8
#define NB ((N_NODES + 255) >> 8)                 // 391 buckets of 256 nodes
#define NBLK 640
#define EPB ((N_EDGES + NBLK - 1) / NBLK)         // 5000 edges per block

typedef _Float16 f16;
typedef _Float16 f16x2 __attribute__((ext_vector_type(2)));

__device__ __forceinline__ float fast_tanh(float x) {
    x = fminf(20.f, fmaxf(-20.f, x));
    float e = __expf(2.f * x);
    return (e - 1.f) / (e + 1.f);
}

// pack two f32 -> bf16x2 (RNE)
__device__ __forceinline__ unsigned int pack_bf2(float a, float b) {
    unsigned int ua = __float_as_uint(a);
    unsigned int ub = __float_as_uint(b);
    ua += 0x7fffu + ((ua >> 16) & 1u);
    ub += 0x7fffu + ((ub >> 16) & 1u);
    return (ua >> 16) | (ub & 0xffff0000u);
}

__device__ __forceinline__ f16x2 u2h(unsigned int u) { union { unsigned int u; f16x2 h; } c; c.u = u; return c.h; }
__device__ __forceinline__ unsigned int h2u(f16x2 h) { union { unsigned int u; f16x2 h; } c; c.h = h; return c.u; }
__device__ __forceinline__ unsigned int mkh2(float a, float b) {
    f16x2 v; v.x = (f16)a; v.y = (f16)b; return h2u(v);
}

__device__ __forceinline__ float fdot2f(f16x2 a, f16x2 b, float c) {
#if __has_builtin(__builtin_amdgcn_fdot2)
    return __builtin_amdgcn_fdot2(a, b, c, false);
#else
    return c + (float)a.x * (float)b.x + (float)a.y * (float)b.y;
#endif
}

// ---------------- CSR build: two-level counting sort, LDS atomics only ----------------

__global__ __launch_bounds__(256) void k_hist(const int* __restrict__ dst,
                                              int* __restrict__ bucket_cnt,
                                              int* __restrict__ blockoff) {
    __shared__ int hist[NB];
    int tid = threadIdx.x;
    int b = blockIdx.x;
    for (int i = tid; i < NB; i += 256) hist[i] = 0;
    __syncthreads();
    int lo = b * EPB;
    int hi = min(lo + EPB, N_EDGES);
    for (int e = lo + tid; e < hi; e += 256)
        atomicAdd(&hist[dst[e] >> BSHIFT], 1);
    __syncthreads();
    for (int i = tid; i < NB; i += 256) {
        int c = hist[i];
        blockoff[b * NB + i] = (c > 0) ? atomicAdd(&bucket_cnt[i], c) : 0;
    }
}

__global__ __launch_bounds__(512) void k_scan_buckets(const int* __restrict__ bucket_cnt,
                                                      int* __restrict__ bucket_base) {
    __shared__ int sd[512];
    int tid = threadIdx.x;
    int v = (tid < NB) ? bucket_cnt[tid] : 0;
    int val = v;
    sd[tid] = val;
    __syncthreads();
#pragma unroll
    for (int off = 1; off < 512; off <<= 1) {
        int t = (tid >= off) ? sd[tid - off] : 0;
        __syncthreads();
        val += t;
        sd[tid] = val;
        __syncthreads();
    }
    if (tid < NB) {
        bucket_base[tid] = val - v;
        if (tid == NB - 1) bucket_base[NB] = val;
    }
}

__global__ __launch_bounds__(256) void k_scatter_buckets(const int* __restrict__ src,
                                                         const int* __restrict__ dst,
                                                         const int* __restrict__ bucket_base,
                                                         const int* __restrict__ blockoff,
                                                         int* __restrict__ ebuf) {
    __shared__ int base[NB];
    __shared__ int cur[NB];
    int tid = threadIdx.x;
    int b = blockIdx.x;
    for (int i = tid; i < NB; i += 256) {
        base[i] = bucket_base[i] + blockoff[b * NB + i];
        cur[i] = 0;
    }
    __syncthreads();
    int lo = b * EPB;
    int hi = min(lo + EPB, N_EDGES);
    for (int e = lo + tid; e < hi; e += 256) {
        int d = dst[e];
        int bin = d >> BSHIFT;
        int r = atomicAdd(&cur[bin], 1);
        ebuf[base[bin] + r] = src[e] | ((d & 255) << 17);
    }
}

__global__ __launch_bounds__(256) void k_bucket_csr(const int* __restrict__ ebuf,
                                                    const int* __restrict__ bucket_base,
                                                    int* __restrict__ rowptr,
                                                    int* __restrict__ rowend,
                                                    int* __restrict__ elist) {
    __shared__ int cnt[256];
    __shared__ int nb[256];
    __shared__ int cur[256];
    __shared__ int sscan[256];
    int b = blockIdx.x;
    int tid = threadIdx.x;
    int e0 = bucket_base[b];
    int e1 = bucket_base[b + 1];
    cnt[tid] = 0;
    cur[tid] = 0;
    __syncthreads();
    for (int j = e0 + tid; j < e1; j += 256)
        atomicAdd(&cnt[ebuf[j] >> 17], 1);
    __syncthreads();
    int v = cnt[tid];
    int val = v;
    sscan[tid] = val;
    __syncthreads();
#pragma unroll
    for (int off = 1; off < 256; off <<= 1) {
        int t = (tid >= off) ? sscan[tid - off] : 0;
        __syncthreads();
        val += t;
        sscan[tid] = val;
        __syncthreads();
    }
    int excl = val - v;
    nb[tid] = excl;
    int node = (b << BSHIFT) + tid;
    if (node < N_NODES) {
        rowptr[node] = e0 + excl;
        rowend[node] = e0 + val;
    }
    __syncthreads();
    for (int j = e0 + tid; j < e1; j += 256) {
        int w = ebuf[j];
        int dl = w >> 17;
        int r = atomicAdd(&cur[dl], 1);
        elist[e0 + nb[dl] + r] = w & 0x1FFFF;
    }
}

// ---------------- cast f32 x -> 3 bf16-pair slice tables: [N][8], [N][8], [N][3] ----------------
__global__ __launch_bounds__(256) void k_cast_slices(const float* __restrict__ in,
                                                     unsigned int* __restrict__ s0,
                                                     unsigned int* __restrict__ s1,
                                                     unsigned int* __restrict__ s2) {
    int i = blockIdx.x * 256 + threadIdx.x;
    if (i >= N_NODES * 19) return;
    int n = i / 19;
    int p = i - n * 19;
    float2 v = ((const float2*)in)[i];      // row of 38 f32 = 19 float2, rows 8B-aligned
    unsigned int w = pack_bf2(v.x, v.y);
    if (p < 8)       s0[n * 8 + p] = w;
    else if (p < 16) s1[n * 8 + p - 8] = w;
    else             s2[n * 3 + p - 16] = w;
}

// ---------------- sliced gather (bf16 pairs): agg[n][OFF+2p..] += sum feat[elist[j]][p] ----------------
template<int DIM2, int ASTRIDE, int OFF>
__global__ __launch_bounds__(256) void k_gather_slice(const unsigned int* __restrict__ feat,
                                                      const int* __restrict__ rowptr,
                                                      const int* __restrict__ rowend,
                                                      const int* __restrict__ elist,
                                                      float* __restrict__ agg) {
    int idx = blockIdx.x * 256 + threadIdx.x;
    if (idx >= N_NODES * DIM2) return;
    int n = idx / DIM2;
    int p = idx - n * DIM2;
    int j = rowptr[n];
    int e = rowend[n];
    float a0 = 0.f, a1 = 0.f;
    for (; j + 3 < e; j += 4) {
        int s0 = elist[j];
        int s1 = elist[j + 1];
        int s2 = elist[j + 2];
        int s3 = elist[j + 3];
        unsigned int w0 = feat[s0 * DIM2 + p];
        unsigned int w1 = feat[s1 * DIM2 + p];
        unsigned int w2 = feat[s2 * DIM2 + p];
        unsigned int w3 = feat[s3 * DIM2 + p];
        a0 += __uint_as_float(w0 << 16);
        a1 += __uint_as_float(w0 & 0xffff0000u);
        a0 += __uint_as_float(w1 << 16);
        a1 += __uint_as_float(w1 & 0xffff0000u);
        a0 += __uint_as_float(w2 << 16);
        a1 += __uint_as_float(w2 & 0xffff0000u);
        a0 += __uint_as_float(w3 << 16);
        a1 += __uint_as_float(w3 & 0xffff0000u);
    }
    for (; j < e; ++j) {
        unsigned int w = feat[elist[j] * DIM2 + p];
        a0 += __uint_as_float(w << 16);
        a1 += __uint_as_float(w & 0xffff0000u);
    }
    agg[n * ASTRIDE + OFF + 2 * p]     = a0;
    agg[n * ASTRIDE + OFF + 2 * p + 1] = a1;
}

// -------- fused layer0+layer1-dense (f16 dot2, node-pair sharing, lane-half split) --------
__global__ __launch_bounds__(256) void k_fused0(const float* __restrict__ agg,   // [N][38]
                                                const float* __restrict__ x,     // [N][38]
                                                const float* __restrict__ Wrel0,
                                                const float* __restrict__ b0,
                                                const float* __restrict__ Wroot0,
                                                const float* __restrict__ Wrel1,
                                                const float* __restrict__ b1,
                                                const float* __restrict__ Wroot1,
                                                unsigned int* __restrict__ y1b0, // [N][8] bf16 pairs (j 0..15)
                                                unsigned int* __restrict__ y1b1, // [N][8] bf16 pairs (j 16..31)
                                                float* __restrict__ r1) {        // [N][32]
    __shared__ unsigned int sWr[64 * 20];   // Wrel0 rows as f16 pairs, K padded 38->40
    __shared__ unsigned int sWt[64 * 20];   // Wroot0
    __shared__ unsigned int sW1r[32 * 32];  // Wrel1 packed pairs along o: [op][j]
    __shared__ unsigned int sW1t[32 * 32];  // Wroot1
    __shared__ float sb0[64];
    __shared__ float sb1[32];
    int tid = threadIdx.x;
    for (int i = tid; i < 64 * 20; i += 256) {
        int o = i / 20, d = i - o * 20;
        float a0 = (2 * d     < 38) ? Wrel0[o * 38 + 2 * d]     : 0.f;
        float a1 = (2 * d + 1 < 38) ? Wrel0[o * 38 + 2 * d + 1] : 0.f;
        float t0 = (2 * d     < 38) ? Wroot0[o * 38 + 2 * d]     : 0.f;
        float t1 = (2 * d + 1 < 38) ? Wroot0[o * 38 + 2 * d + 1] : 0.f;
        sWr[i] = mkh2(a0, a1);
        sWt[i] = mkh2(t0, t1);
    }
    for (int i = tid; i < 32 * 32; i += 256) {
        int op = i >> 5, j = i & 31;
        sW1r[i] = mkh2(Wrel1[j * 64 + 2 * op], Wrel1[j * 64 + 2 * op + 1]);
        sW1t[i] = mkh2(Wroot1[j * 64 + 2 * op], Wroot1[j * 64 + 2 * op + 1]);
    }
    if (tid < 64) sb0[tid] = b0[tid];
    if (tid < 32) sb1[tid] = b1[tid];
    __syncthreads();

    int lane = tid & 63;
    int ph = lane & 31;            // node-pair index within wave
    int sh = lane >> 5;            // split half (o-half / j-half)
    int n0 = blockIdx.x * 256 + (tid >> 6) * 64 + 2 * ph;
    if (n0 >= N_NODES) return;     // both sh-halves of a pair exit together
    int n1 = n0 + 1;               // N even, n0 even -> n1 valid

    // pack both nodes' inputs to f16 pairs in registers (20 dwords each)
    unsigned int xa0[20], xx0[20], xa1[20], xx1[20];
    {
        const float2* A0 = (const float2*)(agg + (size_t)n0 * 38);
        const float2* X0 = (const float2*)(x   + (size_t)n0 * 38);
        const float2* A1 = (const float2*)(agg + (size_t)n1 * 38);
        const float2* X1 = (const float2*)(x   + (size_t)n1 * 38);
#pragma unroll
        for (int i = 0; i < 19; ++i) {
            float2 v;
            v = A0[i]; xa0[i] = mkh2(v.x, v.y);
            v = X0[i]; xx0[i] = mkh2(v.x, v.y);
            v = A1[i]; xa1[i] = mkh2(v.x, v.y);
            v = X1[i]; xx1[i] = mkh2(v.x, v.y);
        }
        xa0[19] = 0; xx0[19] = 0; xa1[19] = 0; xx1[19] = 0;
    }

    // ---- phase A: h1 for my 32 o's, both nodes ----
    unsigned int hp0[16], hp1[16];
    int obase = sh * 32;
#pragma unroll
    for (int i = 0; i < 16; ++i) {
        float h00 = 0.f, h01 = 0.f, h10 = 0.f, h11 = 0.f;
#pragma unroll
        for (int par = 0; par < 2; ++par) {
            int o = obase + 2 * i + par;
            float c0 = sb0[o], c1 = 0.f, c2 = 0.f, c3 = 0.f;
            float d0 = sb0[o], d1 = 0.f, d2 = 0.f, d3 = 0.f;
            const uint4* wr = (const uint4*)(sWr + o * 20);
            const uint4* wt = (const uint4*)(sWt + o * 20);
#pragma unroll
            for (int q = 0; q < 5; ++q) {
                uint4 w = wr[q];
                c0 = fdot2f(u2h(xa0[4 * q + 0]), u2h(w.x), c0);
                c1 = fdot2f(u2h(xa0[4 * q + 1]), u2h(w.y), c1);
                c2 = fdot2f(u2h(xa0[4 * q + 2]), u2h(w.z), c2);
                c3 = fdot2f(u2h(xa0[4 * q + 3]), u2h(w.w), c3);
                d0 = fdot2f(u2h(xa1[4 * q + 0]), u2h(w.x), d0);
                d1 = fdot2f(u2h(xa1[4 * q + 1]), u2h(w.y), d1);
                d2 = fdot2f(u2h(xa1[4 * q + 2]), u2h(w.z), d2);
                d3 = fdot2f(u2h(xa1[4 * q + 3]), u2h(w.w), d3);
                uint4 v = wt[q];
                c0 = fdot2f(u2h(xx0[4 * q + 0]), u2h(v.x), c0);
                c1 = fdot2f(u2h(xx0[4 * q + 1]), u2h(v.y), c1);
                c2 = fdot2f(u2h(xx0[4 * q + 2]), u2h(v.z), c2);
                c3 = fdot2f(u2h(xx0[4 * q + 3]), u2h(v.w), c3);
                d0 = fdot2f(u2h(xx1[4 * q + 0]), u2h(v.x), d0);
                d1 = fdot2f(u2h(xx1[4 * q + 1]), u2h(v.y), d1);
                d2 = fdot2f(u2h(xx1[4 * q + 2]), u2h(v.z), d2);
                d3 = fdot2f(u2h(xx1[4 * q + 3]), u2h(v.w), d3);
            }
            float hA = fast_tanh(c0 + c1 + c2 + c3);
            float hB = fast_tanh(d0 + d1 + d2 + d3);
            if (par == 0) { h00 = hA; h10 = hB; }
            else          { h01 = hA; h11 = hB; }
        }
        hp0[i] = mkh2(h00, h01);
        hp1[i] = mkh2(h10, h11);
    }

    // ---- exchange h-halves within the lane pair ----
    unsigned int H0[32], H1[32];
#pragma unroll
    for (int i = 0; i < 16; ++i) {
        unsigned int g0 = (unsigned int)__shfl_xor((int)hp0[i], 32);
        unsigned int g1 = (unsigned int)__shfl_xor((int)hp1[i], 32);
        if (sh == 0) { H0[i] = hp0[i]; H0[16 + i] = g0; H1[i] = hp1[i]; H1[16 + i] = g1; }
        else         { H0[i] = g0; H0[16 + i] = hp0[i]; H1[i] = g1; H1[16 + i] = hp1[i]; }
    }

    // ---- phase B: my 16 j's, both nodes ----
    int jb = sh * 16;
    float y0[16], r0[16], y1v[16], r1v[16];
#pragma unroll
    for (int j = 0; j < 16; ++j) {
        y0[j] = 0.f; y1v[j] = 0.f;
        float bb = sb1[jb + j];
        r0[j] = bb; r1v[j] = bb;
    }
#pragma unroll
    for (int op = 0; op < 32; ++op) {
        f16x2 h0 = u2h(H0[op]);
        f16x2 h1 = u2h(H1[op]);
        const uint4* w1 = (const uint4*)(sW1r + op * 32 + jb);
        const uint4* w2 = (const uint4*)(sW1t + op * 32 + jb);
#pragma unroll
        for (int q = 0; q < 4; ++q) {
            uint4 a = w1[q], b = w2[q];
            y0[4 * q + 0] = fdot2f(h0, u2h(a.x), y0[4 * q + 0]);
            y0[4 * q + 1] = fdot2f(h0, u2h(a.y), y0[4 * q + 1]);
            y0[4 * q + 2] = fdot2f(h0, u2h(a.z), y0[4 * q + 2]);
            y0[4 * q + 3] = fdot2f(h0, u2h(a.w), y0[4 * q + 3]);
            y1v[4 * q + 0] = fdot2f(h1, u2h(a.x), y1v[4 * q + 0]);
            y1v[4 * q + 1] = fdot2f(h1, u2h(a.y), y1v[4 * q + 1]);
            y1v[4 * q + 2] = fdot2f(h1, u2h(a.z), y1v[4 * q + 2]);
            y1v[4 * q + 3] = fdot2f(h1, u2h(a.w), y1v[4 * q + 3]);
            r0[4 * q + 0] = fdot2f(h0, u2h(b.x), r0[4 * q + 0]);
            r0[4 * q + 1] = fdot2f(h0, u2h(b.y), r0[4 * q + 1]);
            r0[4 * q + 2] = fdot2f(h0, u2h(b.z), r0[4 * q + 2]);
            r0[4 * q + 3] = fdot2f(h0, u2h(b.w), r0[4 * q + 3]);
            r1v[4 * q + 0] = fdot2f(h1, u2h(b.x), r1v[4 * q + 0]);
            r1v[4 * q + 1] = fdot2f(h1, u2h(b.y), r1v[4 * q + 1]);
            r1v[4 * q + 2] = fdot2f(h1, u2h(b.z), r1v[4 * q + 2]);
            r1v[4 * q + 3] = fdot2f(h1, u2h(b.w), r1v[4 * q + 3]);
        }
    }

    // ---- stores: lane's j-range [jb, jb+16) is exactly slice sh; both nodes ----
    unsigned int* yo0 = (sh ? y1b1 : y1b0) + (size_t)n0 * 8;
    unsigned int* yo1 = (sh ? y1b1 : y1b0) + (size_t)n1 * 8;
#pragma unroll
    for (int p = 0; p < 8; ++p) {
        yo0[p] = pack_bf2(y0[2 * p], y0[2 * p + 1]);
        yo1[p] = pack_bf2(y1v[2 * p], y1v[2 * p + 1]);
    }
    float4* ro0 = (float4*)(r1 + (size_t)n0 * 32 + jb);
    float4* ro1 = (float4*)(r1 + (size_t)n1 * 32 + jb);
#pragma unroll
    for (int q = 0; q < 4; ++q) {
        ro0[q] = make_float4(r0[4 * q], r0[4 * q + 1], r0[4 * q + 2], r0[4 * q + 3]);
        ro1[q] = make_float4(r1v[4 * q], r1v[4 * q + 1], r1v[4 * q + 2], r1v[4 * q + 3]);
    }
}

// -------- fused layer1-finish + layer2-rel --------
__global__ __launch_bounds__(256) void k_fused1(const float* __restrict__ agg,   // [N][32]
                                                const float* __restrict__ r1,    // [N][32]
                                                const float* __restrict__ Wrel2, // [16][32]
                                                float* __restrict__ h2,          // [N][32]
                                                unsigned int* __restrict__ y2b)  // [N][8]
{
    __shared__ float sW[32 * 16];   // transposed [k][j]
    int tid = threadIdx.x;
    for (int i = tid; i < 512; i += 256) {
        int k = i >> 4, j = i & 15;
        sW[i] = Wrel2[j * 32 + k];
    }
    __syncthreads();
    int n = blockIdx.x * 256 + tid;
    if (n >= N_NODES) return;
    const float4* a4 = (const float4*)(agg + (size_t)n * 32);
    const float4* r4 = (const float4*)(r1 + (size_t)n * 32);
    float h[32];
#pragma unroll
    for (int i = 0; i < 8; ++i) {
        float4 a = a4[i], r = r4[i];
        h[4 * i]     = fast_tanh(a.x + r.x);
        h[4 * i + 1] = fast_tanh(a.y + r.y);
        h[4 * i + 2] = fast_tanh(a.z + r.z);
        h[4 * i + 3] = fast_tanh(a.w + r.w);
    }
    float4* ho = (float4*)(h2 + (size_t)n * 32);
#pragma unroll
    for (int i = 0; i < 8; ++i) ho[i] = make_float4(h[4 * i], h[4 * i + 1], h[4 * i + 2], h[4 * i + 3]);
    float y[16];
#pragma unroll
    for (int j = 0; j < 16; ++j) y[j] = 0.f;
#pragma unroll
    for (int k = 0; k < 32; ++k) {
        const float4* w = (const float4*)(sW + k * 16);
#pragma unroll
        for (int j = 0; j < 4; ++j) {
            float4 wv = w[j];
            y[4 * j]     += h[k] * wv.x; y[4 * j + 1] += h[k] * wv.y;
            y[4 * j + 2] += h[k] * wv.z; y[4 * j + 3] += h[k] * wv.w;
        }
    }
    unsigned int* yo = y2b + (size_t)n * 8;
#pragma unroll
    for (int p = 0; p < 8; ++p) yo[p] = pack_bf2(y[2 * p], y[2 * p + 1]);
}

// -------- graph boundaries from sorted batch vector --------
__global__ __launch_bounds__(256) void k_graph_start(const int* __restrict__ batch,
                                                     int* __restrict__ gstart) {
    int i = blockIdx.x * 256 + threadIdx.x;
    if (i >= N_NODES) return;
    int g = batch[i];
    int gp = (i == 0) ? -1 : batch[i - 1];
    for (int gg = gp + 1; gg <= g; ++gg) gstart[gg] = i;
    if (i == N_NODES - 1)
        for (int gg = g + 1; gg <= N_GRAPHS; ++gg) gstart[gg] = N_NODES;
}

// -------- per-graph sums of agg[16] and h2[32], no atomics (batch sorted) --------
__global__ __launch_bounds__(256) void k_pool(const float* __restrict__ agg,   // [N][16]
                                              const float* __restrict__ h2,    // [N][32]
                                              const int* __restrict__ gstart,
                                              float* __restrict__ psum)        // [G][48]
{
    __shared__ float part[4][48];
    int g = blockIdx.x;
    int wave = threadIdx.x >> 6;
    int lane = threadIdx.x & 63;
    int s = gstart[g], e = gstart[g + 1];
    if (lane < 48) {
        float a0 = 0.f, a1 = 0.f;
        if (lane < 16) {
            int n = s + wave;
            for (; n + 4 < e; n += 8) {
                a0 += agg[n * 16 + lane];
                a1 += agg[(n + 4) * 16 + lane];
            }
            if (n < e) a0 += agg[n * 16 + lane];
        } else {
            int d = lane - 16;
            int n = s + wave;
            for (; n + 4 < e; n += 8) {
                a0 += h2[n * 32 + d];
                a1 += h2[(n + 4) * 32 + d];
            }
            if (n < e) a0 += h2[n * 32 + d];
        }
        part[wave][lane] = a0 + a1;
    }
    __syncthreads();
    if (threadIdx.x < 48)
        psum[g * 48 + threadIdx.x] = part[0][threadIdx.x] + part[1][threadIdx.x]
                                   + part[2][threadIdx.x] + part[3][threadIdx.x];
}

// -------- finalize: out[g][o] = tanh((psum16[o] + cnt*b[o] + psum32 . W[o]) / cnt) --------
__global__ __launch_bounds__(256) void k_finalize2(const float* __restrict__ psum,  // [G][48]
                                                   const float* __restrict__ Wroot, // [16][32]
                                                   const float* __restrict__ b,
                                                   const int* __restrict__ gstart,
                                                   float* __restrict__ out) {
    __shared__ float sW[16 * 32];
    __shared__ float sb[16];
    int tid = threadIdx.x;
    for (int i = tid; i < 16 * 32; i += 256) sW[i] = Wroot[i];
    if (tid < 16) sb[tid] = b[tid];
    __syncthreads();
    int idx = blockIdx.x * 256 + tid;   // (g, o)
    if (idx >= N_GRAPHS * 16) return;
    int g = idx >> 4;
    int o = idx & 15;
    float cnt = (float)(gstart[g + 1] - gstart[g]);
    const float* p = psum + g * 48;
    float acc = p[o] + cnt * sb[o];
#pragma unroll
    for (int k = 0; k < 32; ++k) acc += p[16 + k] * sW[o * 32 + k];
    out[idx] = fast_tanh(acc / fmaxf(cnt, 1.f));
}

extern "C" void kernel_launch(void* const* d_in, const int* in_sizes, int n_in,
                              void* d_out, int out_size, void* d_ws, size_t ws_size,
                              hipStream_t stream) {
    const float* x      = (const float*)d_in[0];
    const int*   eidx   = (const int*)d_in[1];
    const int*   src    = eidx;
    const int*   dst    = eidx + N_EDGES;
    const int*   batch  = (const int*)d_in[2];
    const float* Wrel0  = (const float*)d_in[3];
    const float* b0     = (const float*)d_in[4];
    const float* Wroot0 = (const float*)d_in[5];
    const float* Wrel1  = (const float*)d_in[6];
    const float* b1     = (const float*)d_in[7];
    const float* Wroot1 = (const float*)d_in[8];
    const float* Wrel2  = (const float*)d_in[9];
    const float* b2     = (const float*)d_in[10];
    const float* Wroot2 = (const float*)d_in[11];
    float* out = (float*)d_out;

    // ---- workspace layout ----
    float* ws   = (float*)d_ws;
    float* agg  = ws;                                  // N*38 f32 (reused 38/32/16)
    float* r1   = agg + (size_t)N_NODES * 38;          // N*32 f32 (alias: x slice tables before fused0)
    float* h2   = r1  + (size_t)N_NODES * 32;          // N*32 f32 (alias: ebuf during CSR build)
    unsigned int* ybuf = (unsigned int*)(h2 + (size_t)N_NODES * 32); // N*16 uints
    float* psum = (float*)(ybuf + (size_t)N_NODES * 16);             // 256*48
    int* rowptr      = (int*)(psum + N_GRAPHS * 48);   // N
    int* rowend      = rowptr + N_NODES;               // N
    int* gstart      = rowend + N_NODES;               // 257 (pad 260)
    int* bucket_cnt  = gstart + 260;                   // NB (pad 400)
    int* bucket_base = bucket_cnt + 400;               // NB+1 (pad 400)
    int* blockoff    = bucket_base + 400;              // NBLK*NB
    int* elist       = blockoff + (size_t)NBLK * NB;   // E
    int* ebuf        = (int*)h2;                       // E (alias; dead before h2 is written)
    // x slice tables alias r1 (N*19 dwords <= N*32; dead after layer-0 gathers, before fused0 writes r1)
    unsigned int* xb0 = (unsigned int*)r1;             // [N][8]
    unsigned int* xb1 = xb0 + (size_t)N_NODES * 8;     // [N][8]
    unsigned int* xb2 = xb1 + (size_t)N_NODES * 8;     // [N][3]
    // y1 slice tables in ybuf; y2b reuses slice0 region after gather16 passes
    unsigned int* y1b0 = ybuf;                         // [N][8]
    unsigned int* y1b1 = ybuf + (size_t)N_NODES * 8;   // [N][8]
    unsigned int* y2b  = ybuf;                         // [N][8]

    // ---- cast x to 3 bf16 slice tables ----
    k_cast_slices<<<(N_NODES * 19 + 255) / 256, 256, 0, stream>>>(x, xb0, xb1, xb2);

    // ---- CSR build + graph boundaries ----
    hipMemsetAsync(bucket_cnt, 0, sizeof(int) * NB, stream);
    k_hist<<<NBLK, 256, 0, stream>>>(dst, bucket_cnt, blockoff);
    k_scan_buckets<<<1, 512, 0, stream>>>(bucket_cnt, bucket_base);
    k_scatter_buckets<<<NBLK, 256, 0, stream>>>(src, dst, bucket_base, blockoff, ebuf);
    k_bucket_csr<<<NB, 256, 0, stream>>>(ebuf, bucket_base, rowptr, rowend, elist);
    k_graph_start<<<(N_NODES + 255) / 256, 256, 0, stream>>>(batch, gstart);

    // ---- Layer 0: 3 L2-resident slice gathers (tables 3.2/3.2/1.2 MB), then fused dense ----
    k_gather_slice<8, 38, 0 ><<<(N_NODES * 8 + 255) / 256, 256, 0, stream>>>(xb0, rowptr, rowend, elist, agg);
    k_gather_slice<8, 38, 16><<<(N_NODES * 8 + 255) / 256, 256, 0, stream>>>(xb1, rowptr, rowend, elist, agg);
    k_gather_slice<3, 38, 32><<<(N_NODES * 3 + 255) / 256, 256, 0, stream>>>(xb2, rowptr, rowend, elist, agg);
    k_fused0<<<(N_NODES + 255) / 256, 256, 0, stream>>>(agg, x, Wrel0, b0, Wroot0,
                                                        Wrel1, b1, Wroot1, y1b0, y1b1, r1);

    // ---- Layer 1: 2 slice gathers (3.2 MB each), then fused finish + layer2-rel ----
    k_gather_slice<8, 32, 0 ><<<(N_NODES * 8 + 255) / 256, 256, 0, stream>>>(y1b0, rowptr, rowend, elist, agg);
    k_gather_slice<8, 32, 16><<<(N_NODES * 8 + 255) / 256, 256, 0, stream>>>(y1b1, rowptr, rowend, elist, agg);
    k_fused1<<<(N_NODES + 255) / 256, 256, 0, stream>>>(agg, r1, Wrel2, h2, y2b);

    // ---- Layer 2: single gather (table 3.2 MB, already L2-resident) ----
    k_gather_slice<8, 16, 0 ><<<(N_NODES * 8 + 255) / 256, 256, 0, stream>>>(y2b, rowptr, rowend, elist, agg);

    // ---- pool: per-graph sums (no atomics), then tiny finalize ----
    k_pool<<<N_GRAPHS, 256, 0, stream>>>(agg, h2, gstart, psum);
    k_finalize2<<<(N_GRAPHS * 16 + 255) / 256, 256, 0, stream>>>(psum, Wroot2, b2, gstart, out);
}